// Round 2
// baseline (3312.897 us; speedup 1.0000x reference)
//
#include <hip/hip_runtime.h>

typedef unsigned short u16;
typedef unsigned int u32;
typedef __attribute__((ext_vector_type(8))) short bf16x8;
typedef __attribute__((ext_vector_type(4))) float f32x4;

#define MFMA(a, b, c) __builtin_amdgcn_mfma_f32_16x16x32_bf16(a, b, c, 0, 0, 0)

__device__ __forceinline__ u16 f2bf(float x) {
    union { float f; u32 u; } v; v.f = x;
    u32 r = (v.u + 0x7FFFu + ((v.u >> 16) & 1u)) >> 16;
    return (u16)r;
}
__device__ __forceinline__ float bf2f(u16 b) {
    union { u32 u; float f; } v; v.u = ((u32)b) << 16;
    return v.f;
}

// ---------------------------------------------------------------------------
// prep: convert LSTM weights to bf16, combine biases
__global__ __launch_bounds__(256) void prep_w(
    const float* __restrict__ Whh_f, const float* __restrict__ Whh_b,
    const float* __restrict__ Wih_f, const float* __restrict__ Wih_b,
    const float* __restrict__ bih_f, const float* __restrict__ bhh_f,
    const float* __restrict__ bih_b, const float* __restrict__ bhh_b,
    u16* __restrict__ WhhB, u16* __restrict__ WihB, float* __restrict__ BS)
{
    int i = blockIdx.x * 256 + threadIdx.x;
    if (i < 131072) {
        int d = i >> 16, r = i & 65535;
        WhhB[i] = f2bf(d ? Whh_b[r] : Whh_f[r]);
    } else if (i < 196608) {
        int i2 = i - 131072; int d = i2 >> 15, r = i2 & 32767;
        WihB[i2] = f2bf(d ? Wih_b[r] : Wih_f[r]);
    } else if (i < 197632) {
        int i3 = i - 196608; int d = i3 >> 9, g = i3 & 511;
        BS[i3] = d ? (bih_b[g] + bhh_b[g]) : (bih_f[g] + bhh_f[g]);
    }
}

// ---------------------------------------------------------------------------
__global__ __launch_bounds__(256) void deg_kernel(const int* __restrict__ dst,
                                                  float* __restrict__ deg, long E)
{
    long i = (long)blockIdx.x * 256 + threadIdx.x;
    if (i < E) atomicAdd(&deg[dst[i]], 1.0f);
}

// ---------------------------------------------------------------------------
// rowgemm: outb[M x 64] (bf16) = act(in[M x K] @ W[64 x K]^T (+ bias*scale))
template <int K, bool RELU>
__global__ __launch_bounds__(256) void rowgemm(
    const float* __restrict__ in, const float* __restrict__ W,
    const float* __restrict__ bias, const float* __restrict__ bias_scale,
    u16* __restrict__ outb, int M)
{
    constexpr int KP = K + 8;  // row stride: KP*2 bytes, multiple of 16
    __shared__ u16 inS[64 * KP];
    __shared__ u16 WS[64 * KP];
    int t = threadIdx.x;
    long rb = (long)blockIdx.x * 64;
    for (int i = t; i < 64 * K; i += 256) {
        int c = i / K, k = i - c * K;
        WS[c * KP + k] = f2bf(W[i]);
    }
    for (int i = t; i < 64 * K; i += 256) {
        int r = i / K, k = i - r * K;
        long gr = rb + r;
        inS[r * KP + k] = (gr < M) ? f2bf(in[gr * (long)K + k]) : (u16)0;
    }
    __syncthreads();
    int l = t & 63, w = t >> 6, lr = l & 15, lq = l >> 4;
    f32x4 acc[4];
#pragma unroll
    for (int i = 0; i < 4; ++i) acc[i] = (f32x4){0.f, 0.f, 0.f, 0.f};
#pragma unroll
    for (int kc = 0; kc < K; kc += 32) {
        bf16x8 a = *(const bf16x8*)&inS[(w * 16 + lr) * KP + kc + lq * 8];
#pragma unroll
        for (int ct = 0; ct < 4; ++ct) {
            bf16x8 b = *(const bf16x8*)&WS[(ct * 16 + lr) * KP + kc + lq * 8];
            acc[ct] = MFMA(a, b, acc[ct]);
        }
    }
#pragma unroll
    for (int ct = 0; ct < 4; ++ct)
#pragma unroll
        for (int r = 0; r < 4; ++r) {
            long gr = rb + w * 16 + lq * 4 + r;
            if (gr < M) {
                int c = ct * 16 + lr;
                float v = acc[ct][r];
                if (bias) v += bias[c] * (bias_scale ? bias_scale[gr] : 1.f);
                if (RELU) v = fmaxf(v, 0.f);
                outb[gr * 64 + c] = f2bf(v);
            }
        }
}

// ---------------------------------------------------------------------------
// edge_msg: per edge e: m = relu([feat[src]|feat[dst]|attr[e]] @ W[64x144]^T)
//  ATOMIC=false (init): plain-store bf16 row to outb[e], fp32 atomicAdd into
//                       agg[ei[E+e]] (node aggregation, fused).
//  ATOMIC=true  (lg layers): packed-bf16 CAS-accumulate into outb[ei[E+e]].
//                            (avg in-degree 1 -> near-zero CAS retries)
template <bool ATOMIC>
__global__ __launch_bounds__(256) void edge_msg(
    const u16* __restrict__ feat, const int* __restrict__ ei,
    const float* __restrict__ attr, const float* __restrict__ W,
    u16* __restrict__ outb, float* __restrict__ agg, long E)
{
    __shared__ u16 inS[128 * 168];   // 43008 B; reused as eds[128*64] in epilogue
    __shared__ u16 WS[64 * 168];     // 21504 B
    int t = threadIdx.x;
    long eb = (long)blockIdx.x * 128;
    for (int i = t; i < 64 * 144; i += 256) {
        int c = i / 144, k = i - c * 144;
        WS[c * 168 + k] = f2bf(W[i]);
    }
    for (int i = t; i < 64 * 24; i += 256) {
        int c = i / 24, k = 144 + (i - c * 24);
        WS[c * 168 + k] = 0;
    }
    {
        int le = t >> 1, half = t & 1;
        long e = eb + le;
        bool ok = (e < E);
        if (half == 0) {
            int src = ok ? ei[e] : 0;
            const uint4* sp = (const uint4*)(feat + (long)src * 64);
            u16* dp = &inS[le * 168];
#pragma unroll
            for (int j = 0; j < 8; ++j) {
                uint4 v = ok ? sp[j] : make_uint4(0, 0, 0, 0);
                *(uint4*)(dp + j * 8) = v;
            }
        } else {
            int dst = ok ? ei[E + e] : 0;
            const uint4* sp = (const uint4*)(feat + (long)dst * 64);
            u16* dp = &inS[le * 168 + 64];
#pragma unroll
            for (int j = 0; j < 8; ++j) {
                uint4 v = ok ? sp[j] : make_uint4(0, 0, 0, 0);
                *(uint4*)(dp + j * 8) = v;
            }
            const float4* ap = (const float4*)(attr + e * 16);
            u16* dq = &inS[le * 168 + 128];
#pragma unroll
            for (int j = 0; j < 4; ++j) {
                float4 v = ok ? ap[j] : make_float4(0.f, 0.f, 0.f, 0.f);
                dq[j * 4 + 0] = f2bf(v.x); dq[j * 4 + 1] = f2bf(v.y);
                dq[j * 4 + 2] = f2bf(v.z); dq[j * 4 + 3] = f2bf(v.w);
            }
            u16* dz = &inS[le * 168 + 144];
#pragma unroll
            for (int j = 0; j < 3; ++j) *(uint4*)(dz + j * 8) = make_uint4(0, 0, 0, 0);
        }
    }
    __syncthreads();
    int l = t & 63, w = t >> 6, lr = l & 15, lq = l >> 4;
    f32x4 acc[2][4];
#pragma unroll
    for (int et = 0; et < 2; ++et)
#pragma unroll
        for (int ct = 0; ct < 4; ++ct) acc[et][ct] = (f32x4){0.f, 0.f, 0.f, 0.f};
#pragma unroll
    for (int kc = 0; kc < 160; kc += 32) {
        bf16x8 a0 = *(const bf16x8*)&inS[(w * 32 + lr) * 168 + kc + lq * 8];
        bf16x8 a1 = *(const bf16x8*)&inS[(w * 32 + 16 + lr) * 168 + kc + lq * 8];
#pragma unroll
        for (int ct = 0; ct < 4; ++ct) {
            bf16x8 b = *(const bf16x8*)&WS[(ct * 16 + lr) * 168 + kc + lq * 8];
            acc[0][ct] = MFMA(a0, b, acc[0][ct]);
            acc[1][ct] = MFMA(a1, b, acc[1][ct]);
        }
    }
    __syncthreads();   // inS dead; reuse as eds[128 rows][64 cols]
    u16* eds = inS;
#pragma unroll
    for (int et = 0; et < 2; ++et)
#pragma unroll
        for (int ct = 0; ct < 4; ++ct)
#pragma unroll
            for (int r = 0; r < 4; ++r) {
                int row = w * 32 + et * 16 + lq * 4 + r;
                int col = ct * 16 + lr;
                eds[row * 64 + col] = f2bf(fmaxf(acc[et][ct][r], 0.f));
            }
    __syncthreads();
    for (int j = t; j < 4096; j += 256) {
        int le = j >> 5, wd = j & 31;
        long e = eb + le;
        if (e >= E) continue;
        u32 pair = *(const u32*)&eds[le * 64 + wd * 2];
        if (ATOMIC) {
            if (pair != 0u) {
                long dn = ei[E + e];
                u32* dstw = (u32*)(outb + dn * 64 + wd * 2);
                float lo = bf2f((u16)(pair & 0xFFFFu));
                float hi = bf2f((u16)(pair >> 16));
                u32 old = *dstw, assumed;
                do {
                    assumed = old;
                    float nlo = bf2f((u16)(assumed & 0xFFFFu)) + lo;
                    float nhi = bf2f((u16)(assumed >> 16)) + hi;
                    u32 des = (u32)f2bf(nlo) | ((u32)f2bf(nhi) << 16);
                    if (des == assumed) break;
                    old = atomicCAS(dstw, assumed, des);
                } while (old != assumed);
            }
        } else {
            *(u32*)(outb + e * 64 + wd * 2) = pair;
            if (agg) {
                long dn = ei[E + e];
                float* ap = agg + dn * 64 + wd * 2;
                atomicAdd(ap + 0, bf2f((u16)(pair & 0xFFFFu)));
                atomicAdd(ap + 1, bf2f((u16)(pair >> 16)));
            }
        }
    }
}

// ---------------------------------------------------------------------------
// aggnode: fp32 atomic scatter of bf16 msg rows into node agg by g-dst.
__global__ __launch_bounds__(256) void aggnode(
    const u16* __restrict__ m, const int* __restrict__ dstg,
    float* __restrict__ agg, long E)
{
    long idx = (long)blockIdx.x * 256 + threadIdx.x;
    if (idx >= E * 16) return;
    long e = idx >> 4; int q = (int)(idx & 15);
    uint2 p = *(const uint2*)(m + e * 64 + q * 4);
    long dn = dstg[e];
    float* ap = agg + dn * 64 + q * 4;
    atomicAdd(ap + 0, bf2f((u16)(p.x & 0xFFFFu)));
    atomicAdd(ap + 1, bf2f((u16)(p.x >> 16)));
    atomicAdd(ap + 2, bf2f((u16)(p.y & 0xFFFFu)));
    atomicAdd(ap + 3, bf2f((u16)(p.y >> 16)));
}

// ---------------------------------------------------------------------------
// Fused bidirectional LSTM (one dir per blockIdx.y), 32 nodes/block.
__global__ __launch_bounds__(256) void lstm_kernel(
    const u16* __restrict__ jkB, const u16* __restrict__ WhhB,
    const u16* __restrict__ WihB, const float* __restrict__ BS,
    const float* __restrict__ Watt, float* __restrict__ scores, int N)
{
    __shared__ u16 Wc[512 * 40];   // one 32-wide k-chunk of 512 gate rows
    __shared__ u16 hS[32 * 136];
    __shared__ u16 xS[32 * 72];
    __shared__ float WattS[128];
    __shared__ float part[32 * 8];
    int t = threadIdx.x;
    int dir = blockIdx.y;
    long n0 = (long)blockIdx.x * 32;
    const u16* WhhD = WhhB + (long)dir * 65536;
    const u16* WihD = WihB + (long)dir * 32768;
    int l = t & 63, w = t >> 6, lr = l & 15, lq = l >> 4;
    for (int i = t; i < 32 * 136; i += 256) hS[i] = 0;
    if (t < 128) WattS[t] = Watt[dir * 128 + t];
    float bs[4][2];
#pragma unroll
    for (int ty = 0; ty < 4; ++ty)
#pragma unroll
        for (int ut = 0; ut < 2; ++ut)
            bs[ty][ut] = BS[dir * 512 + ty * 128 + w * 32 + ut * 16 + lr];
    float creg[2][2][4] = {};
    float* scOut = scores + (long)dir * N * 4;

    for (int s = 0; s < 4; ++s) {
        int tt = dir ? (3 - s) : s;
        f32x4 acc[4][2][2];
#pragma unroll
        for (int ty = 0; ty < 4; ++ty)
#pragma unroll
            for (int ut = 0; ut < 2; ++ut)
#pragma unroll
                for (int nt = 0; nt < 2; ++nt) {
                    float b0 = bs[ty][ut];
                    acc[ty][ut][nt] = (f32x4){b0, b0, b0, b0};
                }
        for (int ch = 0; ch < 6; ++ch) {
            __syncthreads();
            const u16* wsrc; int wk0, wK;
            if (ch < 4) { wsrc = WhhD; wk0 = ch * 32; wK = 128; }
            else        { wsrc = WihD; wk0 = (ch - 4) * 32; wK = 64; }
            for (int i = t; i < 4096; i += 256) {
                int g = i >> 3, jj = i & 7;
                *(uint2*)&Wc[g * 40 + jj * 4] = *(const uint2*)&wsrc[g * wK + wk0 + jj * 4];
            }
            if (ch == 0) {
                int n = t >> 3, j = t & 7;   // 256 threads = 32 nodes x 8 x uint4
                long gn = n0 + n;
                uint4 v = make_uint4(0, 0, 0, 0);
                if (gn < N) v = *(const uint4*)&jkB[((long)tt * N + gn) * 64 + j * 8];
                *(uint4*)&xS[n * 72 + j * 8] = v;
            }
            __syncthreads();
            bf16x8 a[2];
            if (ch < 4) {
#pragma unroll
                for (int nt = 0; nt < 2; ++nt)
                    a[nt] = *(const bf16x8*)&hS[(nt * 16 + lr) * 136 + ch * 32 + lq * 8];
            } else {
#pragma unroll
                for (int nt = 0; nt < 2; ++nt)
                    a[nt] = *(const bf16x8*)&xS[(nt * 16 + lr) * 72 + (ch - 4) * 32 + lq * 8];
            }
#pragma unroll
            for (int ty = 0; ty < 4; ++ty)
#pragma unroll
                for (int ut = 0; ut < 2; ++ut) {
                    int g = ty * 128 + w * 32 + ut * 16 + lr;
                    bf16x8 b = *(const bf16x8*)&Wc[g * 40 + lq * 8];
                    acc[ty][ut][0] = MFMA(a[0], b, acc[ty][ut][0]);
                    acc[ty][ut][1] = MFMA(a[1], b, acc[ty][ut][1]);
                }
        }
        __syncthreads();
#pragma unroll
        for (int ut = 0; ut < 2; ++ut)
#pragma unroll
            for (int nt = 0; nt < 2; ++nt)
#pragma unroll
                for (int r = 0; r < 4; ++r) {
                    float iv = acc[0][ut][nt][r], fv = acc[1][ut][nt][r];
                    float gv = acc[2][ut][nt][r], ov = acc[3][ut][nt][r];
                    float c = creg[ut][nt][r];
                    float si = 1.f / (1.f + __expf(-iv));
                    float sf = 1.f / (1.f + __expf(-fv));
                    float tg = 2.f / (1.f + __expf(-2.f * gv)) - 1.f;
                    c = sf * c + si * tg;
                    float so = 1.f / (1.f + __expf(-ov));
                    float th = 2.f / (1.f + __expf(-2.f * c)) - 1.f;
                    creg[ut][nt][r] = c;
                    int nl = nt * 16 + lq * 4 + r;
                    int u = w * 32 + ut * 16 + lr;
                    hS[nl * 136 + u] = f2bf(so * th);
                }
        __syncthreads();
        {
            int n = t & 31, ck = t >> 5;
            float sum = 0.f;
#pragma unroll
            for (int j = 0; j < 16; ++j)
                sum += bf2f(hS[n * 136 + ck * 16 + j]) * WattS[ck * 16 + j];
            part[n * 8 + ck] = sum;
        }
        __syncthreads();
        if (t < 32) {
            long gn = n0 + t;
            if (gn < N) {
                float v = 0.f;
#pragma unroll
                for (int j = 0; j < 8; ++j) v += part[t * 8 + j];
                scOut[gn * 4 + tt] = v;
            }
        }
    }
}

// ---------------------------------------------------------------------------
__global__ __launch_bounds__(256) void final_kernel(
    const u16* __restrict__ jkB, const float* __restrict__ scores,
    const float* __restrict__ Wout, float* __restrict__ out, int N)
{
    __shared__ float feS[4][64];
    int t = threadIdx.x, l = t & 63, w = t >> 6;
    long n = (long)blockIdx.x * 4 + w;
    bool ok = (n < N);
    long nn = ok ? n : (long)(N - 1);
    float sc[4];
#pragma unroll
    for (int tt = 0; tt < 4; ++tt)
        sc[tt] = scores[nn * 4 + tt] + scores[(long)N * 4 + nn * 4 + tt];
    float m = fmaxf(fmaxf(sc[0], sc[1]), fmaxf(sc[2], sc[3]));
    float e0 = __expf(sc[0] - m), e1 = __expf(sc[1] - m);
    float e2 = __expf(sc[2] - m), e3 = __expf(sc[3] - m);
    float den = e0 + e1 + e2 + e3;
    float a0 = e0 / den, a1 = e1 / den, a2 = e2 / den, a3 = e3 / den;
    float fe = a0 * bf2f(jkB[nn * 64 + l]) + a1 * bf2f(jkB[((long)N + nn) * 64 + l]) +
               a2 * bf2f(jkB[((long)2 * N + nn) * 64 + l]) +
               a3 * bf2f(jkB[((long)3 * N + nn) * 64 + l]);
    feS[w][l] = fe;
    __syncthreads();
    float logit = 0.f;
    if (l < 40)
        for (int c = 0; c < 64; ++c) logit += feS[w][c] * Wout[l * 64 + c];
    float v = (l < 40) ? logit : -1e30f;
    for (int off = 32; off; off >>= 1) v = fmaxf(v, __shfl_xor(v, off));
    float ex = (l < 40) ? __expf(logit - v) : 0.f;
    for (int off = 32; off; off >>= 1) ex += __shfl_xor(ex, off);
    if (ok && l < 40) out[n * 40 + l] = logit - v - __logf(ex);
}

// ---------------------------------------------------------------------------
extern "C" void kernel_launch(void* const* d_in, const int* in_sizes, int n_in,
                              void* d_out, int out_size, void* d_ws, size_t ws_size,
                              hipStream_t stream)
{
    const float* x        = (const float*)d_in[0];
    const int*   eig      = (const int*)d_in[1];
    const float* eag      = (const float*)d_in[2];
    const int*   eilg     = (const int*)d_in[3];
    const float* ealg     = (const float*)d_in[4];
    const float* W_feat   = (const float*)d_in[5];
    const float* W_msg    = (const float*)d_in[6];
    const float* W_lg2g   = (const float*)d_in[7];
    const float* b_lg2g   = (const float*)d_in[8];
    const float* W_msg_l  = (const float*)d_in[9];
    const float* Wih_f    = (const float*)d_in[10];
    const float* Whh_f    = (const float*)d_in[11];
    const float* bih_f    = (const float*)d_in[12];
    const float* bhh_f    = (const float*)d_in[13];
    const float* Wih_b    = (const float*)d_in[14];
    const float* Whh_b    = (const float*)d_in[15];
    const float* bih_b    = (const float*)d_in[16];
    const float* bhh_b    = (const float*)d_in[17];
    const float* W_att    = (const float*)d_in[18];
    const float* W_out    = (const float*)d_in[20];

    int  N   = in_sizes[0] / 128;
    long Eg  = in_sizes[1] / 2;
    long Elg = in_sizes[3] / 2;

    char* wp = (char*)d_ws;
    auto alloc = [&](size_t bytes) -> char* {
        char* p = wp; wp += (bytes + 255) & ~(size_t)255; return p;
    };
    // total ~245.4 MB
    u16*   jkB    = (u16*)  alloc((size_t)4 * N * 64 * 2);   // [4][N][64] bf16
    u16*   mA     = (u16*)  alloc((size_t)Eg * 64 * 2);      // msg bf16 ping
    u16*   mB     = (u16*)  alloc((size_t)Eg * 64 * 2);      // msg bf16 pong
    float* agg    = (float*)alloc((size_t)N * 64 * 4);
    float* deg    = (float*)alloc((size_t)N * 4);
    float* scores = (float*)alloc((size_t)2 * N * 4 * 4);
    u16*   WhhB   = (u16*)  alloc((size_t)2 * 65536 * 2);
    u16*   WihB   = (u16*)  alloc((size_t)2 * 32768 * 2);
    float* BS     = (float*)alloc((size_t)2 * 512 * 4);

    hipMemsetAsync(agg, 0, (size_t)N * 64 * 4, stream);
    hipMemsetAsync(deg, 0, (size_t)N * 4, stream);
    prep_w<<<772, 256, 0, stream>>>(Whh_f, Whh_b, Wih_f, Wih_b,
                                    bih_f, bhh_f, bih_b, bhh_b, WhhB, WihB, BS);
    // jk0 = relu(x @ W_feat^T)  (bf16; also the gather source for init msgs)
    rowgemm<128, true><<<(N + 63) / 64, 256, 0, stream>>>(
        x, W_feat, nullptr, nullptr, jkB, N);
    deg_kernel<<<(int)((Eg + 255) / 256), 256, 0, stream>>>(eig + Eg, deg, Eg);
    // initial msgs -> mA, fused node agg
    edge_msg<false><<<(int)((Eg + 127) / 128), 256, 0, stream>>>(
        jkB, eig, eag, W_msg, mA, agg, Eg);
    // jk1 = agg @ W_lg2g^T + deg*b
    rowgemm<64, false><<<(N + 63) / 64, 256, 0, stream>>>(
        agg, W_lg2g, b_lg2g, deg, jkB + (size_t)N * 64, N);
    // ---- linegraph layer 0: mA -> mB ----
    hipMemsetAsync(mB, 0, (size_t)Eg * 64 * 2, stream);
    edge_msg<true><<<(int)((Elg + 127) / 128), 256, 0, stream>>>(
        mA, eilg, ealg, W_msg_l, mB, nullptr, Elg);
    hipMemsetAsync(agg, 0, (size_t)N * 64 * 4, stream);
    aggnode<<<(int)((Eg * 16 + 255) / 256), 256, 0, stream>>>(mB, eig + Eg, agg, Eg);
    rowgemm<64, false><<<(N + 63) / 64, 256, 0, stream>>>(
        agg, W_lg2g, b_lg2g, nullptr, jkB + (size_t)2 * N * 64, N);
    // ---- linegraph layer 1: mB -> mA ----
    hipMemsetAsync(mA, 0, (size_t)Eg * 64 * 2, stream);
    edge_msg<true><<<(int)((Elg + 127) / 128), 256, 0, stream>>>(
        mB, eilg, ealg, W_msg_l + 64 * 144, mA, nullptr, Elg);
    hipMemsetAsync(agg, 0, (size_t)N * 64 * 4, stream);
    aggnode<<<(int)((Eg * 16 + 255) / 256), 256, 0, stream>>>(mA, eig + Eg, agg, Eg);
    rowgemm<64, false><<<(N + 63) / 64, 256, 0, stream>>>(
        agg, W_lg2g, b_lg2g, nullptr, jkB + (size_t)3 * N * 64, N);
    // ---- JK bidirectional LSTM + attention scores ----
    lstm_kernel<<<dim3((N + 31) / 32, 2), 256, 0, stream>>>(
        jkB, WhhB, WihB, BS, W_att, scores, N);
    final_kernel<<<(N + 3) / 4, 256, 0, stream>>>(
        jkB, scores, W_out, (float*)d_out, N);
}

// Round 3
// 1775.170 us; speedup vs baseline: 1.8662x; 1.8662x over previous
//
#include <hip/hip_runtime.h>

typedef unsigned short u16;
typedef unsigned int u32;
typedef __attribute__((ext_vector_type(8))) short bf16x8;
typedef __attribute__((ext_vector_type(4))) float f32x4;

#define MFMA(a, b, c) __builtin_amdgcn_mfma_f32_16x16x32_bf16(a, b, c, 0, 0, 0)

__device__ __forceinline__ u16 f2bf(float x) {
    union { float f; u32 u; } v; v.f = x;
    u32 r = (v.u + 0x7FFFu + ((v.u >> 16) & 1u)) >> 16;
    return (u16)r;
}
__device__ __forceinline__ float bf2f(u16 b) {
    union { u32 u; float f; } v; v.u = ((u32)b) << 16;
    return v.f;
}
__device__ __forceinline__ void casAddPair(u32* w, float lo, float hi) {
    u32 old = *w, assumed;
    do {
        assumed = old;
        u32 des = (u32)f2bf(bf2f((u16)(assumed & 0xFFFFu)) + lo) |
                  ((u32)f2bf(bf2f((u16)(assumed >> 16)) + hi) << 16);
        if (des == assumed) break;
        old = atomicCAS(w, assumed, des);
    } while (old != assumed);
}

// ---------------------------------------------------------------------------
// prep: convert LSTM weights to bf16, combine biases
__global__ __launch_bounds__(256) void prep_w(
    const float* __restrict__ Whh_f, const float* __restrict__ Whh_b,
    const float* __restrict__ Wih_f, const float* __restrict__ Wih_b,
    const float* __restrict__ bih_f, const float* __restrict__ bhh_f,
    const float* __restrict__ bih_b, const float* __restrict__ bhh_b,
    u16* __restrict__ WhhB, u16* __restrict__ WihB, float* __restrict__ BS)
{
    int i = blockIdx.x * 256 + threadIdx.x;
    if (i < 131072) {
        int d = i >> 16, r = i & 65535;
        WhhB[i] = f2bf(d ? Whh_b[r] : Whh_f[r]);
    } else if (i < 196608) {
        int i2 = i - 131072; int d = i2 >> 15, r = i2 & 32767;
        WihB[i2] = f2bf(d ? Wih_b[r] : Wih_f[r]);
    } else if (i < 197632) {
        int i3 = i - 196608; int d = i3 >> 9, g = i3 & 511;
        BS[i3] = d ? (bih_b[g] + bhh_b[g]) : (bih_f[g] + bhh_f[g]);
    }
}

// ---------------------------------------------------------------------------
// CSR build: count -> 3-phase exclusive scan -> fill (fill corrupts offsets
// into end-offsets; gather uses off[n-1]..off[n] with off[-1]=0).
__global__ __launch_bounds__(256) void count_kernel(const int* __restrict__ dst,
                                                    u32* __restrict__ cnt, long E)
{
    long i = (long)blockIdx.x * 256 + threadIdx.x;
    if (i < E) atomicAdd(&cnt[dst[i]], 1u);
}

__global__ __launch_bounds__(256) void scan1(const u32* __restrict__ a,
                                             u32* __restrict__ part, int n)
{
    __shared__ u32 ts[256];
    int b = blockIdx.x, t = threadIdx.x;
    long i0 = (long)b * 1024 + t * 4;
    u32 s = 0;
#pragma unroll
    for (int k = 0; k < 4; ++k) { long i = i0 + k; if (i < n) s += a[i]; }
    ts[t] = s; __syncthreads();
    for (int off = 1; off < 256; off <<= 1) {
        u32 x = (t >= off) ? ts[t - off] : 0u;
        __syncthreads(); ts[t] += x; __syncthreads();
    }
    if (t == 255) part[b] = ts[255];
}

__global__ __launch_bounds__(1024) void scan2(u32* __restrict__ part, int nb,
                                              u32* __restrict__ total_out)
{
    __shared__ u32 ts[1024];
    int t = threadIdx.x;
    u32 v = (t < nb) ? part[t] : 0u;
    ts[t] = v; __syncthreads();
    for (int off = 1; off < 1024; off <<= 1) {
        u32 x = (t >= off) ? ts[t - off] : 0u;
        __syncthreads(); ts[t] += x; __syncthreads();
    }
    if (t < nb) part[t] = ts[t] - v;
    if (t == 1023 && total_out) *total_out = ts[1023];
}

__global__ __launch_bounds__(256) void scan3(u32* __restrict__ a,
                                             const u32* __restrict__ part, int n)
{
    __shared__ u32 ts[256];
    int b = blockIdx.x, t = threadIdx.x;
    long i0 = (long)b * 1024 + t * 4;
    u32 v[4]; u32 s = 0;
#pragma unroll
    for (int k = 0; k < 4; ++k) { long i = i0 + k; v[k] = (i < n) ? a[i] : 0u; s += v[k]; }
    ts[t] = s; __syncthreads();
    for (int off = 1; off < 256; off <<= 1) {
        u32 x = (t >= off) ? ts[t - off] : 0u;
        __syncthreads(); ts[t] += x; __syncthreads();
    }
    u32 run = part[b] + ts[t] - s;
#pragma unroll
    for (int k = 0; k < 4; ++k) {
        long i = i0 + k;
        if (i < n) { u32 x = v[k]; a[i] = run; run += x; }
    }
}

__global__ __launch_bounds__(256) void fill_kernel(const int* __restrict__ dst,
                                                   u32* __restrict__ off,
                                                   int* __restrict__ list, long E)
{
    long i = (long)blockIdx.x * 256 + threadIdx.x;
    if (i < E) {
        u32 pos = atomicAdd(&off[dst[i]], 1u);
        list[pos] = (int)i;
    }
}

// ---------------------------------------------------------------------------
// rowgemm: outb[M x 64] (bf16) = act(in[M x K] @ W[64 x K]^T (+ bias*scale))
template <int K, bool RELU, bool INBF16>
__global__ __launch_bounds__(256) void rowgemm(
    const void* __restrict__ in, const float* __restrict__ W,
    const float* __restrict__ bias, const float* __restrict__ bias_scale,
    u16* __restrict__ outb, int M)
{
    constexpr int KP = K + 8;
    __shared__ u16 inS[64 * KP];
    __shared__ u16 WS[64 * KP];
    int t = threadIdx.x;
    long rb = (long)blockIdx.x * 64;
    for (int i = t; i < 64 * K; i += 256) {
        int c = i / K, k = i - c * K;
        WS[c * KP + k] = f2bf(W[i]);
    }
    if (INBF16) {
        const u16* inb = (const u16*)in;
        for (int i = t; i < 64 * K / 8; i += 256) {
            int r = i / (K / 8), q = i - r * (K / 8);
            long gr = rb + r;
            uint4 v = make_uint4(0, 0, 0, 0);
            if (gr < M) v = *(const uint4*)&inb[gr * (long)K + q * 8];
            *(uint4*)&inS[r * KP + q * 8] = v;
        }
    } else {
        const float* inf = (const float*)in;
        for (int i = t; i < 64 * K; i += 256) {
            int r = i / K, k = i - r * K;
            long gr = rb + r;
            inS[r * KP + k] = (gr < M) ? f2bf(inf[gr * (long)K + k]) : (u16)0;
        }
    }
    __syncthreads();
    int l = t & 63, w = t >> 6, lr = l & 15, lq = l >> 4;
    f32x4 acc[4];
#pragma unroll
    for (int i = 0; i < 4; ++i) acc[i] = (f32x4){0.f, 0.f, 0.f, 0.f};
#pragma unroll
    for (int kc = 0; kc < K; kc += 32) {
        bf16x8 a = *(const bf16x8*)&inS[(w * 16 + lr) * KP + kc + lq * 8];
#pragma unroll
        for (int ct = 0; ct < 4; ++ct) {
            bf16x8 b = *(const bf16x8*)&WS[(ct * 16 + lr) * KP + kc + lq * 8];
            acc[ct] = MFMA(a, b, acc[ct]);
        }
    }
#pragma unroll
    for (int ct = 0; ct < 4; ++ct)
#pragma unroll
        for (int r = 0; r < 4; ++r) {
            long gr = rb + w * 16 + lq * 4 + r;
            if (gr < M) {
                int c = ct * 16 + lr;
                float v = acc[ct][r];
                if (bias) v += bias[c] * (bias_scale ? bias_scale[gr] : 1.f);
                if (RELU) v = fmaxf(v, 0.f);
                outb[gr * 64 + c] = f2bf(v);
            }
        }
}

// ---------------------------------------------------------------------------
// edge_msg_init: e in natural order; m=relu([feat[src]|feat[dst]|attr]@W^T)
// plain bf16 row stores to outb[e]. No atomics.
__global__ __launch_bounds__(256) void edge_msg_init(
    const u16* __restrict__ feat, const int* __restrict__ ei,
    const float* __restrict__ attr, const float* __restrict__ W,
    u16* __restrict__ outb, long E)
{
    __shared__ u16 inS[128 * 168];
    __shared__ u16 WS[64 * 168];
    int t = threadIdx.x;
    long eb = (long)blockIdx.x * 128;
    for (int i = t; i < 64 * 144; i += 256) {
        int c = i / 144, k = i - c * 144;
        WS[c * 168 + k] = f2bf(W[i]);
    }
    for (int i = t; i < 64 * 24; i += 256) {
        int c = i / 24, k = 144 + (i - c * 24);
        WS[c * 168 + k] = 0;
    }
    {
        int le = t >> 1, half = t & 1;
        long e = eb + le;
        bool ok = (e < E);
        if (half == 0) {
            int src = ok ? ei[e] : 0;
            const uint4* sp = (const uint4*)(feat + (long)src * 64);
            u16* dp = &inS[le * 168];
#pragma unroll
            for (int j = 0; j < 8; ++j) {
                uint4 v = ok ? sp[j] : make_uint4(0, 0, 0, 0);
                *(uint4*)(dp + j * 8) = v;
            }
        } else {
            int dst = ok ? ei[E + e] : 0;
            const uint4* sp = (const uint4*)(feat + (long)dst * 64);
            u16* dp = &inS[le * 168 + 64];
#pragma unroll
            for (int j = 0; j < 8; ++j) {
                uint4 v = ok ? sp[j] : make_uint4(0, 0, 0, 0);
                *(uint4*)(dp + j * 8) = v;
            }
            const float4* ap = (const float4*)(attr + e * 16);
            u16* dq = &inS[le * 168 + 128];
#pragma unroll
            for (int j = 0; j < 4; ++j) {
                float4 v = ok ? ap[j] : make_float4(0.f, 0.f, 0.f, 0.f);
                dq[j * 4 + 0] = f2bf(v.x); dq[j * 4 + 1] = f2bf(v.y);
                dq[j * 4 + 2] = f2bf(v.z); dq[j * 4 + 3] = f2bf(v.w);
            }
            u16* dz = &inS[le * 168 + 144];
#pragma unroll
            for (int j = 0; j < 3; ++j) *(uint4*)(dz + j * 8) = make_uint4(0, 0, 0, 0);
        }
    }
    __syncthreads();
    int l = t & 63, w = t >> 6, lr = l & 15, lq = l >> 4;
    f32x4 acc[2][4];
#pragma unroll
    for (int et = 0; et < 2; ++et)
#pragma unroll
        for (int ct = 0; ct < 4; ++ct) acc[et][ct] = (f32x4){0.f, 0.f, 0.f, 0.f};
#pragma unroll
    for (int kc = 0; kc < 160; kc += 32) {
        bf16x8 a0 = *(const bf16x8*)&inS[(w * 32 + lr) * 168 + kc + lq * 8];
        bf16x8 a1 = *(const bf16x8*)&inS[(w * 32 + 16 + lr) * 168 + kc + lq * 8];
#pragma unroll
        for (int ct = 0; ct < 4; ++ct) {
            bf16x8 b = *(const bf16x8*)&WS[(ct * 16 + lr) * 168 + kc + lq * 8];
            acc[0][ct] = MFMA(a0, b, acc[0][ct]);
            acc[1][ct] = MFMA(a1, b, acc[1][ct]);
        }
    }
    __syncthreads();
    u16* eds = inS;
#pragma unroll
    for (int et = 0; et < 2; ++et)
#pragma unroll
        for (int ct = 0; ct < 4; ++ct)
#pragma unroll
            for (int r = 0; r < 4; ++r) {
                int row = w * 32 + et * 16 + lq * 4 + r;
                int col = ct * 16 + lr;
                eds[row * 64 + col] = f2bf(fmaxf(acc[et][ct][r], 0.f));
            }
    __syncthreads();
    for (int j = t; j < 1024; j += 256) {
        int le = j >> 3, q = j & 7;
        long e = eb + le;
        if (e < E)
            *(uint4*)(outb + e * 64 + q * 8) = *(const uint4*)&eds[le * 64 + q * 8];
    }
}

// ---------------------------------------------------------------------------
// edge_msg_lg: edges processed in dst-sorted (CSR-permuted) order.
// Block-local segmented reduction; plain store for complete segments,
// bf16-CAS only at block boundaries. outb must be pre-zeroed.
__global__ __launch_bounds__(256) void edge_msg_lg(
    const u16* __restrict__ feat, const int* __restrict__ ei,
    const float* __restrict__ attr, const float* __restrict__ W,
    const int* __restrict__ list, u16* __restrict__ outb, long E)
{
    __shared__ u16 inS[128 * 168];
    __shared__ u16 WS[64 * 168];
    __shared__ int dstS[128];
    __shared__ int idS[128];
    __shared__ int dprevS, dnextS;
    int t = threadIdx.x;
    long pb = (long)blockIdx.x * 128;
    for (int i = t; i < 64 * 144; i += 256) {
        int c = i / 144, k = i - c * 144;
        WS[c * 168 + k] = f2bf(W[i]);
    }
    for (int i = t; i < 64 * 24; i += 256) {
        int c = i / 24, k = 144 + (i - c * 24);
        WS[c * 168 + k] = 0;
    }
    if (t < 128) {
        long p = pb + t;
        int id = (p < E) ? list[p] : -1;
        idS[t] = id;
        dstS[t] = (id >= 0) ? ei[E + id] : -1;
    } else if (t == 128) {
        dprevS = (pb > 0) ? ei[E + list[pb - 1]] : -2;
    } else if (t == 129) {
        dnextS = (pb + 128 < E) ? ei[E + list[pb + 128]] : -2;
    }
    __syncthreads();
    {
        int le = t >> 1, half = t & 1;
        int id = idS[le];
        bool ok = (id >= 0);
        if (half == 0) {
            int src = ok ? ei[id] : 0;
            const uint4* sp = (const uint4*)(feat + (long)src * 64);
            u16* dp = &inS[le * 168];
#pragma unroll
            for (int j = 0; j < 8; ++j) {
                uint4 v = ok ? sp[j] : make_uint4(0, 0, 0, 0);
                *(uint4*)(dp + j * 8) = v;
            }
        } else {
            int dst = ok ? dstS[le] : 0;
            const uint4* sp = (const uint4*)(feat + (long)dst * 64);
            u16* dp = &inS[le * 168 + 64];
#pragma unroll
            for (int j = 0; j < 8; ++j) {
                uint4 v = ok ? sp[j] : make_uint4(0, 0, 0, 0);
                *(uint4*)(dp + j * 8) = v;
            }
            const float4* ap = (const float4*)(attr + (long)id * 16);
            u16* dq = &inS[le * 168 + 128];
#pragma unroll
            for (int j = 0; j < 4; ++j) {
                float4 v = ok ? ap[j] : make_float4(0.f, 0.f, 0.f, 0.f);
                dq[j * 4 + 0] = f2bf(v.x); dq[j * 4 + 1] = f2bf(v.y);
                dq[j * 4 + 2] = f2bf(v.z); dq[j * 4 + 3] = f2bf(v.w);
            }
            u16* dz = &inS[le * 168 + 144];
#pragma unroll
            for (int j = 0; j < 3; ++j) *(uint4*)(dz + j * 8) = make_uint4(0, 0, 0, 0);
        }
    }
    __syncthreads();
    int l = t & 63, w = t >> 6, lr = l & 15, lq = l >> 4;
    f32x4 acc[2][4];
#pragma unroll
    for (int et = 0; et < 2; ++et)
#pragma unroll
        for (int ct = 0; ct < 4; ++ct) acc[et][ct] = (f32x4){0.f, 0.f, 0.f, 0.f};
#pragma unroll
    for (int kc = 0; kc < 160; kc += 32) {
        bf16x8 a0 = *(const bf16x8*)&inS[(w * 32 + lr) * 168 + kc + lq * 8];
        bf16x8 a1 = *(const bf16x8*)&inS[(w * 32 + 16 + lr) * 168 + kc + lq * 8];
#pragma unroll
        for (int ct = 0; ct < 4; ++ct) {
            bf16x8 b = *(const bf16x8*)&WS[(ct * 16 + lr) * 168 + kc + lq * 8];
            acc[0][ct] = MFMA(a0, b, acc[0][ct]);
            acc[1][ct] = MFMA(a1, b, acc[1][ct]);
        }
    }
    __syncthreads();
    u16* eds = inS;
#pragma unroll
    for (int et = 0; et < 2; ++et)
#pragma unroll
        for (int ct = 0; ct < 4; ++ct)
#pragma unroll
            for (int r = 0; r < 4; ++r) {
                int row = w * 32 + et * 16 + lq * 4 + r;
                int col = ct * 16 + lr;
                eds[row * 64 + col] = f2bf(fmaxf(acc[et][ct][r], 0.f));
            }
    __syncthreads();
    for (int j = t; j < 4096; j += 256) {
        int le = j >> 5, wd = j & 31;
        int d = dstS[le];
        if (d < 0) continue;
        if (le > 0 && dstS[le - 1] == d) continue;  // not segment start
        float lo = 0.f, hi = 0.f;
        int le2 = le;
        do {
            u32 pair = *(const u32*)&eds[le2 * 64 + wd * 2];
            lo += bf2f((u16)(pair & 0xFFFFu));
            hi += bf2f((u16)(pair >> 16));
            ++le2;
        } while (le2 < 128 && dstS[le2] == d);
        bool bprev = (le == 0 && dprevS == d);
        bool bnext = (le2 == 128 && dnextS == d);
        u32* dw = (u32*)(outb + (long)d * 64 + wd * 2);
        if (bprev || bnext) {
            casAddPair(dw, lo, hi);
        } else {
            *dw = (u32)f2bf(lo) | ((u32)f2bf(hi) << 16);
        }
    }
}

// ---------------------------------------------------------------------------
// gather_g: aggB[n] = sum over CSR bucket of bf16 msg rows (one wave/node).
// offc is the fill-corrupted offset array: bucket n = [offc[n-1], offc[n]).
__global__ __launch_bounds__(256) void gather_g(
    const u16* __restrict__ m, const int* __restrict__ list,
    const u32* __restrict__ offc, u16* __restrict__ aggB,
    float* __restrict__ degOut, int N)
{
    int t = threadIdx.x, w = t >> 6, l = t & 63;
    long n = (long)blockIdx.x * 4 + w;
    if (n >= N) return;
    u32 start = n ? offc[n - 1] : 0u;
    u32 end = offc[n];
    float s = 0.f;
    for (u32 i = start; i < end; ++i) {
        int e = list[i];
        s += bf2f(m[(long)e * 64 + l]);
    }
    aggB[n * 64 + l] = f2bf(s);
    if (degOut && l == 0) degOut[n] = (float)(end - start);
}

// ---------------------------------------------------------------------------
// Fused bidirectional LSTM (one dir per blockIdx.y), 32 nodes/block.
__global__ __launch_bounds__(256) void lstm_kernel(
    const u16* __restrict__ jkB, const u16* __restrict__ WhhB,
    const u16* __restrict__ WihB, const float* __restrict__ BS,
    const float* __restrict__ Watt, float* __restrict__ scores, int N)
{
    __shared__ u16 Wc[512 * 40];
    __shared__ u16 hS[32 * 136];
    __shared__ u16 xS[32 * 72];
    __shared__ float WattS[128];
    __shared__ float part[32 * 8];
    int t = threadIdx.x;
    int dir = blockIdx.y;
    long n0 = (long)blockIdx.x * 32;
    const u16* WhhD = WhhB + (long)dir * 65536;
    const u16* WihD = WihB + (long)dir * 32768;
    int l = t & 63, w = t >> 6, lr = l & 15, lq = l >> 4;
    for (int i = t; i < 32 * 136; i += 256) hS[i] = 0;
    if (t < 128) WattS[t] = Watt[dir * 128 + t];
    float bs[4][2];
#pragma unroll
    for (int ty = 0; ty < 4; ++ty)
#pragma unroll
        for (int ut = 0; ut < 2; ++ut)
            bs[ty][ut] = BS[dir * 512 + ty * 128 + w * 32 + ut * 16 + lr];
    float creg[2][2][4] = {};
    float* scOut = scores + (long)dir * N * 4;

    for (int s = 0; s < 4; ++s) {
        int tt = dir ? (3 - s) : s;
        f32x4 acc[4][2][2];
#pragma unroll
        for (int ty = 0; ty < 4; ++ty)
#pragma unroll
            for (int ut = 0; ut < 2; ++ut)
#pragma unroll
                for (int nt = 0; nt < 2; ++nt) {
                    float b0 = bs[ty][ut];
                    acc[ty][ut][nt] = (f32x4){b0, b0, b0, b0};
                }
        for (int ch = 0; ch < 6; ++ch) {
            __syncthreads();
            const u16* wsrc; int wk0, wK;
            if (ch < 4) { wsrc = WhhD; wk0 = ch * 32; wK = 128; }
            else        { wsrc = WihD; wk0 = (ch - 4) * 32; wK = 64; }
            for (int i = t; i < 4096; i += 256) {
                int g = i >> 3, jj = i & 7;
                *(uint2*)&Wc[g * 40 + jj * 4] = *(const uint2*)&wsrc[g * wK + wk0 + jj * 4];
            }
            if (ch == 0) {
                int n = t >> 3, j = t & 7;
                long gn = n0 + n;
                uint4 v = make_uint4(0, 0, 0, 0);
                if (gn < N) v = *(const uint4*)&jkB[((long)tt * N + gn) * 64 + j * 8];
                *(uint4*)&xS[n * 72 + j * 8] = v;
            }
            __syncthreads();
            bf16x8 a[2];
            if (ch < 4) {
#pragma unroll
                for (int nt = 0; nt < 2; ++nt)
                    a[nt] = *(const bf16x8*)&hS[(nt * 16 + lr) * 136 + ch * 32 + lq * 8];
            } else {
#pragma unroll
                for (int nt = 0; nt < 2; ++nt)
                    a[nt] = *(const bf16x8*)&xS[(nt * 16 + lr) * 72 + (ch - 4) * 32 + lq * 8];
            }
#pragma unroll
            for (int ty = 0; ty < 4; ++ty)
#pragma unroll
                for (int ut = 0; ut < 2; ++ut) {
                    int g = ty * 128 + w * 32 + ut * 16 + lr;
                    bf16x8 b = *(const bf16x8*)&Wc[g * 40 + lq * 8];
                    acc[ty][ut][0] = MFMA(a[0], b, acc[ty][ut][0]);
                    acc[ty][ut][1] = MFMA(a[1], b, acc[ty][ut][1]);
                }
        }
        __syncthreads();
#pragma unroll
        for (int ut = 0; ut < 2; ++ut)
#pragma unroll
            for (int nt = 0; nt < 2; ++nt)
#pragma unroll
                for (int r = 0; r < 4; ++r) {
                    float iv = acc[0][ut][nt][r], fv = acc[1][ut][nt][r];
                    float gv = acc[2][ut][nt][r], ov = acc[3][ut][nt][r];
                    float c = creg[ut][nt][r];
                    float si = 1.f / (1.f + __expf(-iv));
                    float sf = 1.f / (1.f + __expf(-fv));
                    float tg = 2.f / (1.f + __expf(-2.f * gv)) - 1.f;
                    c = sf * c + si * tg;
                    float so = 1.f / (1.f + __expf(-ov));
                    float th = 2.f / (1.f + __expf(-2.f * c)) - 1.f;
                    creg[ut][nt][r] = c;
                    int nl = nt * 16 + lq * 4 + r;
                    int u = w * 32 + ut * 16 + lr;
                    hS[nl * 136 + u] = f2bf(so * th);
                }
        __syncthreads();
        {
            int n = t & 31, ck = t >> 5;
            float sum = 0.f;
#pragma unroll
            for (int j = 0; j < 16; ++j)
                sum += bf2f(hS[n * 136 + ck * 16 + j]) * WattS[ck * 16 + j];
            part[n * 8 + ck] = sum;
        }
        __syncthreads();
        if (t < 32) {
            long gn = n0 + t;
            if (gn < N) {
                float v = 0.f;
#pragma unroll
                for (int j = 0; j < 8; ++j) v += part[t * 8 + j];
                scOut[gn * 4 + tt] = v;
            }
        }
    }
}

// ---------------------------------------------------------------------------
__global__ __launch_bounds__(256) void final_kernel(
    const u16* __restrict__ jkB, const float* __restrict__ scores,
    const float* __restrict__ Wout, float* __restrict__ out, int N)
{
    __shared__ float feS[4][64];
    int t = threadIdx.x, l = t & 63, w = t >> 6;
    long n = (long)blockIdx.x * 4 + w;
    bool ok = (n < N);
    long nn = ok ? n : (long)(N - 1);
    float sc[4];
#pragma unroll
    for (int tt = 0; tt < 4; ++tt)
        sc[tt] = scores[nn * 4 + tt] + scores[(long)N * 4 + nn * 4 + tt];
    float m = fmaxf(fmaxf(sc[0], sc[1]), fmaxf(sc[2], sc[3]));
    float e0 = __expf(sc[0] - m), e1 = __expf(sc[1] - m);
    float e2 = __expf(sc[2] - m), e3 = __expf(sc[3] - m);
    float den = e0 + e1 + e2 + e3;
    float a0 = e0 / den, a1 = e1 / den, a2 = e2 / den, a3 = e3 / den;
    float fe = a0 * bf2f(jkB[nn * 64 + l]) + a1 * bf2f(jkB[((long)N + nn) * 64 + l]) +
               a2 * bf2f(jkB[((long)2 * N + nn) * 64 + l]) +
               a3 * bf2f(jkB[((long)3 * N + nn) * 64 + l]);
    feS[w][l] = fe;
    __syncthreads();
    float logit = 0.f;
    if (l < 40)
        for (int c = 0; c < 64; ++c) logit += feS[w][c] * Wout[l * 64 + c];
    float v = (l < 40) ? logit : -1e30f;
    for (int off = 32; off; off >>= 1) v = fmaxf(v, __shfl_xor(v, off));
    float ex = (l < 40) ? __expf(logit - v) : 0.f;
    for (int off = 32; off; off >>= 1) ex += __shfl_xor(ex, off);
    if (ok && l < 40) out[n * 40 + l] = logit - v - __logf(ex);
}

// ---------------------------------------------------------------------------
extern "C" void kernel_launch(void* const* d_in, const int* in_sizes, int n_in,
                              void* d_out, int out_size, void* d_ws, size_t ws_size,
                              hipStream_t stream)
{
    const float* x        = (const float*)d_in[0];
    const int*   eig      = (const int*)d_in[1];
    const float* eag      = (const float*)d_in[2];
    const int*   eilg     = (const int*)d_in[3];
    const float* ealg     = (const float*)d_in[4];
    const float* W_feat   = (const float*)d_in[5];
    const float* W_msg    = (const float*)d_in[6];
    const float* W_lg2g   = (const float*)d_in[7];
    const float* b_lg2g   = (const float*)d_in[8];
    const float* W_msg_l  = (const float*)d_in[9];
    const float* Wih_f    = (const float*)d_in[10];
    const float* Whh_f    = (const float*)d_in[11];
    const float* bih_f    = (const float*)d_in[12];
    const float* bhh_f    = (const float*)d_in[13];
    const float* Wih_b    = (const float*)d_in[14];
    const float* Whh_b    = (const float*)d_in[15];
    const float* bih_b    = (const float*)d_in[16];
    const float* bhh_b    = (const float*)d_in[17];
    const float* W_att    = (const float*)d_in[18];
    const float* W_out    = (const float*)d_in[20];

    int  N   = in_sizes[0] / 128;
    long Eg  = in_sizes[1] / 2;
    long Elg = in_sizes[3] / 2;

    char* wp = (char*)d_ws;
    auto alloc = [&](size_t bytes) -> char* {
        char* p = wp; wp += (bytes + 255) & ~(size_t)255; return p;
    };
    // total ~248.8 MB
    u16*   jkB    = (u16*)  alloc((size_t)4 * N * 64 * 2);     // 25.6 MB
    u16*   mA     = (u16*)  alloc((size_t)Eg * 64 * 2);        // 102.4 MB
    u16*   mB     = (u16*)  alloc((size_t)Eg * 64 * 2);        // 102.4 MB
    u16*   aggB   = (u16*)  alloc((size_t)N * 64 * 2);         // 6.4 MB
    float* deg    = (float*)alloc((size_t)N * 4);              // 0.2 MB
    float* scores = (float*)alloc((size_t)2 * N * 4 * 4);      // 1.6 MB
    u16*   WhhB   = (u16*)  alloc((size_t)2 * 65536 * 2);
    u16*   WihB   = (u16*)  alloc((size_t)2 * 32768 * 2);
    float* BS     = (float*)alloc((size_t)2 * 512 * 4);
    u32*   off_g  = (u32*)  alloc((size_t)(N + 1) * 4);        // 0.2 MB
    int*   list_g = (int*)  alloc((size_t)Eg * 4);             // 3.2 MB
    u32*   off_lg = (u32*)  alloc((size_t)(Eg + 1) * 4);       // 3.2 MB
    int*   list_lg= (int*)  alloc((size_t)Elg * 4);            // 3.2 MB
    u32*   part   = (u32*)  alloc((size_t)1024 * 4);

    prep_w<<<772, 256, 0, stream>>>(Whh_f, Whh_b, Wih_f, Wih_b,
                                    bih_f, bhh_f, bih_b, bhh_b, WhhB, WihB, BS);
    // ---- CSR build: g-graph (dst over nodes) ----
    hipMemsetAsync(off_g, 0, (size_t)(N + 1) * 4, stream);
    count_kernel<<<(int)((Eg + 255) / 256), 256, 0, stream>>>(eig + Eg, off_g, Eg);
    {
        int nb = (N + 1023) / 1024;
        scan1<<<nb, 256, 0, stream>>>(off_g, part, N);
        scan2<<<1, 1024, 0, stream>>>(part, nb, off_g + N);
        scan3<<<nb, 256, 0, stream>>>(off_g, part, N);
    }
    fill_kernel<<<(int)((Eg + 255) / 256), 256, 0, stream>>>(eig + Eg, off_g, list_g, Eg);
    // ---- CSR build: lg-graph (dst over g-edges) ----
    hipMemsetAsync(off_lg, 0, (size_t)(Eg + 1) * 4, stream);
    count_kernel<<<(int)((Elg + 255) / 256), 256, 0, stream>>>(eilg + Elg, off_lg, Elg);
    {
        int nb = (int)((Eg + 1023) / 1024);
        scan1<<<nb, 256, 0, stream>>>(off_lg, part, (int)Eg);
        scan2<<<1, 1024, 0, stream>>>(part, nb, off_lg + Eg);
        scan3<<<nb, 256, 0, stream>>>(off_lg, part, (int)Eg);
    }
    fill_kernel<<<(int)((Elg + 255) / 256), 256, 0, stream>>>(eilg + Elg, off_lg, list_lg, Elg);

    // jk0 = relu(x @ W_feat^T)
    rowgemm<128, true, false><<<(N + 63) / 64, 256, 0, stream>>>(
        x, W_feat, nullptr, nullptr, jkB, N);
    // initial msgs -> mA (plain stores)
    edge_msg_init<<<(int)((Eg + 127) / 128), 256, 0, stream>>>(
        jkB, eig, eag, W_msg, mA, Eg);
    // jk1 = gather(mA) @ W_lg2g^T + deg*b
    gather_g<<<(N + 3) / 4, 256, 0, stream>>>(mA, list_g, off_g, aggB, deg, N);
    rowgemm<64, false, true><<<(N + 63) / 64, 256, 0, stream>>>(
        aggB, W_lg2g, b_lg2g, deg, jkB + (size_t)N * 64, N);
    // ---- linegraph layer 0: mA -> mB ----
    hipMemsetAsync(mB, 0, (size_t)Eg * 64 * 2, stream);
    edge_msg_lg<<<(int)((Elg + 127) / 128), 256, 0, stream>>>(
        mA, eilg, ealg, W_msg_l, list_lg, mB, Elg);
    gather_g<<<(N + 3) / 4, 256, 0, stream>>>(mB, list_g, off_g, aggB, nullptr, N);
    rowgemm<64, false, true><<<(N + 63) / 64, 256, 0, stream>>>(
        aggB, W_lg2g, b_lg2g, nullptr, jkB + (size_t)2 * N * 64, N);
    // ---- linegraph layer 1: mB -> mA ----
    hipMemsetAsync(mA, 0, (size_t)Eg * 64 * 2, stream);
    edge_msg_lg<<<(int)((Elg + 127) / 128), 256, 0, stream>>>(
        mB, eilg, ealg, W_msg_l + 64 * 144, list_lg, mA, Elg);
    gather_g<<<(N + 3) / 4, 256, 0, stream>>>(mA, list_g, off_g, aggB, nullptr, N);
    rowgemm<64, false, true><<<(N + 63) / 64, 256, 0, stream>>>(
        aggB, W_lg2g, b_lg2g, nullptr, jkB + (size_t)3 * N * 64, N);
    // ---- JK bidirectional LSTM + attention ----
    lstm_kernel<<<dim3((N + 31) / 32, 2), 256, 0, stream>>>(
        jkB, WhhB, WihB, BS, W_att, scores, N);
    final_kernel<<<(N + 3) / 4, 256, 0, stream>>>(
        jkB, scores, W_out, (float*)d_out, N);
}

// Round 4
// 1486.838 us; speedup vs baseline: 2.2281x; 1.1939x over previous
//
#include <hip/hip_runtime.h>

typedef unsigned short u16;
typedef unsigned int u32;
typedef __attribute__((ext_vector_type(8))) short bf16x8;
typedef __attribute__((ext_vector_type(4))) float f32x4;

#define MFMA(a, b, c) __builtin_amdgcn_mfma_f32_16x16x32_bf16(a, b, c, 0, 0, 0)

__device__ __forceinline__ u16 f2bf(float x) {
    union { float f; u32 u; } v; v.f = x;
    u32 r = (v.u + 0x7FFFu + ((v.u >> 16) & 1u)) >> 16;
    return (u16)r;
}
__device__ __forceinline__ float bf2f(u16 b) {
    union { u32 u; float f; } v; v.u = ((u32)b) << 16;
    return v.f;
}
__device__ __forceinline__ void casAddPair(u32* w, float lo, float hi) {
    u32 old = *w, assumed;
    do {
        assumed = old;
        u32 des = (u32)f2bf(bf2f((u16)(assumed & 0xFFFFu)) + lo) |
                  ((u32)f2bf(bf2f((u16)(assumed >> 16)) + hi) << 16);
        if (des == assumed) break;
        old = atomicCAS(w, assumed, des);
    } while (old != assumed);
}

// ---------------------------------------------------------------------------
// prep: convert LSTM weights to bf16, combine biases
__global__ __launch_bounds__(256) void prep_w(
    const float* __restrict__ Whh_f, const float* __restrict__ Whh_b,
    const float* __restrict__ Wih_f, const float* __restrict__ Wih_b,
    const float* __restrict__ bih_f, const float* __restrict__ bhh_f,
    const float* __restrict__ bih_b, const float* __restrict__ bhh_b,
    u16* __restrict__ WhhB, u16* __restrict__ WihB, float* __restrict__ BS)
{
    int i = blockIdx.x * 256 + threadIdx.x;
    if (i < 131072) {
        int d = i >> 16, r = i & 65535;
        WhhB[i] = f2bf(d ? Whh_b[r] : Whh_f[r]);
    } else if (i < 196608) {
        int i2 = i - 131072; int d = i2 >> 15, r = i2 & 32767;
        WihB[i2] = f2bf(d ? Wih_b[r] : Wih_f[r]);
    } else if (i < 197632) {
        int i3 = i - 196608; int d = i3 >> 9, g = i3 & 511;
        BS[i3] = d ? (bih_b[g] + bhh_b[g]) : (bih_f[g] + bhh_f[g]);
    }
}

// ---------------------------------------------------------------------------
// CSR build: count -> 3-phase exclusive scan -> fill (fill corrupts offsets
// into end-offsets; gather uses off[n-1]..off[n] with off[-1]=0).
__global__ __launch_bounds__(256) void count_kernel(const int* __restrict__ dst,
                                                    u32* __restrict__ cnt, long E)
{
    long i = (long)blockIdx.x * 256 + threadIdx.x;
    if (i < E) atomicAdd(&cnt[dst[i]], 1u);
}

__global__ __launch_bounds__(256) void scan1(const u32* __restrict__ a,
                                             u32* __restrict__ part, int n)
{
    __shared__ u32 ts[256];
    int b = blockIdx.x, t = threadIdx.x;
    long i0 = (long)b * 1024 + t * 4;
    u32 s = 0;
#pragma unroll
    for (int k = 0; k < 4; ++k) { long i = i0 + k; if (i < n) s += a[i]; }
    ts[t] = s; __syncthreads();
    for (int off = 1; off < 256; off <<= 1) {
        u32 x = (t >= off) ? ts[t - off] : 0u;
        __syncthreads(); ts[t] += x; __syncthreads();
    }
    if (t == 255) part[b] = ts[255];
}

__global__ __launch_bounds__(1024) void scan2(u32* __restrict__ part, int nb,
                                              u32* __restrict__ total_out)
{
    __shared__ u32 ts[1024];
    int t = threadIdx.x;
    u32 v = (t < nb) ? part[t] : 0u;
    ts[t] = v; __syncthreads();
    for (int off = 1; off < 1024; off <<= 1) {
        u32 x = (t >= off) ? ts[t - off] : 0u;
        __syncthreads(); ts[t] += x; __syncthreads();
    }
    if (t < nb) part[t] = ts[t] - v;
    if (t == 1023 && total_out) *total_out = ts[1023];
}

__global__ __launch_bounds__(256) void scan3(u32* __restrict__ a,
                                             const u32* __restrict__ part, int n)
{
    __shared__ u32 ts[256];
    int b = blockIdx.x, t = threadIdx.x;
    long i0 = (long)b * 1024 + t * 4;
    u32 v[4]; u32 s = 0;
#pragma unroll
    for (int k = 0; k < 4; ++k) { long i = i0 + k; v[k] = (i < n) ? a[i] : 0u; s += v[k]; }
    ts[t] = s; __syncthreads();
    for (int off = 1; off < 256; off <<= 1) {
        u32 x = (t >= off) ? ts[t - off] : 0u;
        __syncthreads(); ts[t] += x; __syncthreads();
    }
    u32 run = part[b] + ts[t] - s;
#pragma unroll
    for (int k = 0; k < 4; ++k) {
        long i = i0 + k;
        if (i < n) { u32 x = v[k]; a[i] = run; run += x; }
    }
}

__global__ __launch_bounds__(256) void fill_kernel(const int* __restrict__ dst,
                                                   u32* __restrict__ off,
                                                   int* __restrict__ list, long E)
{
    long i = (long)blockIdx.x * 256 + threadIdx.x;
    if (i < E) {
        u32 pos = atomicAdd(&off[dst[i]], 1u);
        list[pos] = (int)i;
    }
}

// ---------------------------------------------------------------------------
// rowgemm: outb[M x 64] (bf16) = act(in[M x K] @ W[64 x K]^T (+ bias*scale))
template <int K, bool RELU, bool INBF16>
__global__ __launch_bounds__(256) void rowgemm(
    const void* __restrict__ in, const float* __restrict__ W,
    const float* __restrict__ bias, const float* __restrict__ bias_scale,
    u16* __restrict__ outb, int M)
{
    constexpr int KP = K + 8;
    __shared__ u16 inS[64 * KP];
    __shared__ u16 WS[64 * KP];
    int t = threadIdx.x;
    long rb = (long)blockIdx.x * 64;
    for (int i = t; i < 64 * K; i += 256) {
        int c = i / K, k = i - c * K;
        WS[c * KP + k] = f2bf(W[i]);
    }
    if (INBF16) {
        const u16* inb = (const u16*)in;
        for (int i = t; i < 64 * K / 8; i += 256) {
            int r = i / (K / 8), q = i - r * (K / 8);
            long gr = rb + r;
            uint4 v = make_uint4(0, 0, 0, 0);
            if (gr < M) v = *(const uint4*)&inb[gr * (long)K + q * 8];
            *(uint4*)&inS[r * KP + q * 8] = v;
        }
    } else {
        const float* inf = (const float*)in;
        for (int i = t; i < 64 * K; i += 256) {
            int r = i / K, k = i - r * K;
            long gr = rb + r;
            inS[r * KP + k] = (gr < M) ? f2bf(inf[gr * (long)K + k]) : (u16)0;
        }
    }
    __syncthreads();
    int l = t & 63, w = t >> 6, lr = l & 15, lq = l >> 4;
    f32x4 acc[4];
#pragma unroll
    for (int i = 0; i < 4; ++i) acc[i] = (f32x4){0.f, 0.f, 0.f, 0.f};
#pragma unroll
    for (int kc = 0; kc < K; kc += 32) {
        bf16x8 a = *(const bf16x8*)&inS[(w * 16 + lr) * KP + kc + lq * 8];
#pragma unroll
        for (int ct = 0; ct < 4; ++ct) {
            bf16x8 b = *(const bf16x8*)&WS[(ct * 16 + lr) * KP + kc + lq * 8];
            acc[ct] = MFMA(a, b, acc[ct]);
        }
    }
#pragma unroll
    for (int ct = 0; ct < 4; ++ct)
#pragma unroll
        for (int r = 0; r < 4; ++r) {
            long gr = rb + w * 16 + lq * 4 + r;
            if (gr < M) {
                int c = ct * 16 + lr;
                float v = acc[ct][r];
                if (bias) v += bias[c] * (bias_scale ? bias_scale[gr] : 1.f);
                if (RELU) v = fmaxf(v, 0.f);
                outb[gr * 64 + c] = f2bf(v);
            }
        }
}

// ---------------------------------------------------------------------------
// edge_msg_init: e in natural order; m=relu([feat[src]|feat[dst]|attr]@W^T)
// plain bf16 row stores to outb[e]. No atomics.
__global__ __launch_bounds__(256) void edge_msg_init(
    const u16* __restrict__ feat, const int* __restrict__ ei,
    const float* __restrict__ attr, const float* __restrict__ W,
    u16* __restrict__ outb, long E)
{
    __shared__ u16 inS[128 * 168];
    __shared__ u16 WS[64 * 168];
    int t = threadIdx.x;
    long eb = (long)blockIdx.x * 128;
    for (int i = t; i < 64 * 144; i += 256) {
        int c = i / 144, k = i - c * 144;
        WS[c * 168 + k] = f2bf(W[i]);
    }
    for (int i = t; i < 64 * 24; i += 256) {
        int c = i / 24, k = 144 + (i - c * 24);
        WS[c * 168 + k] = 0;
    }
    {
        int le = t >> 1, half = t & 1;
        long e = eb + le;
        bool ok = (e < E);
        if (half == 0) {
            int src = ok ? ei[e] : 0;
            const uint4* sp = (const uint4*)(feat + (long)src * 64);
            u16* dp = &inS[le * 168];
#pragma unroll
            for (int j = 0; j < 8; ++j) {
                uint4 v = ok ? sp[j] : make_uint4(0, 0, 0, 0);
                *(uint4*)(dp + j * 8) = v;
            }
        } else {
            int dst = ok ? ei[E + e] : 0;
            const uint4* sp = (const uint4*)(feat + (long)dst * 64);
            u16* dp = &inS[le * 168 + 64];
#pragma unroll
            for (int j = 0; j < 8; ++j) {
                uint4 v = ok ? sp[j] : make_uint4(0, 0, 0, 0);
                *(uint4*)(dp + j * 8) = v;
            }
            const float4* ap = (const float4*)(attr + e * 16);
            u16* dq = &inS[le * 168 + 128];
#pragma unroll
            for (int j = 0; j < 4; ++j) {
                float4 v = ok ? ap[j] : make_float4(0.f, 0.f, 0.f, 0.f);
                dq[j * 4 + 0] = f2bf(v.x); dq[j * 4 + 1] = f2bf(v.y);
                dq[j * 4 + 2] = f2bf(v.z); dq[j * 4 + 3] = f2bf(v.w);
            }
            u16* dz = &inS[le * 168 + 144];
#pragma unroll
            for (int j = 0; j < 3; ++j) *(uint4*)(dz + j * 8) = make_uint4(0, 0, 0, 0);
        }
    }
    __syncthreads();
    int l = t & 63, w = t >> 6, lr = l & 15, lq = l >> 4;
    f32x4 acc[2][4];
#pragma unroll
    for (int et = 0; et < 2; ++et)
#pragma unroll
        for (int ct = 0; ct < 4; ++ct) acc[et][ct] = (f32x4){0.f, 0.f, 0.f, 0.f};
#pragma unroll
    for (int kc = 0; kc < 160; kc += 32) {
        bf16x8 a0 = *(const bf16x8*)&inS[(w * 32 + lr) * 168 + kc + lq * 8];
        bf16x8 a1 = *(const bf16x8*)&inS[(w * 32 + 16 + lr) * 168 + kc + lq * 8];
#pragma unroll
        for (int ct = 0; ct < 4; ++ct) {
            bf16x8 b = *(const bf16x8*)&WS[(ct * 16 + lr) * 168 + kc + lq * 8];
            acc[0][ct] = MFMA(a0, b, acc[0][ct]);
            acc[1][ct] = MFMA(a1, b, acc[1][ct]);
        }
    }
    __syncthreads();
    u16* eds = inS;
#pragma unroll
    for (int et = 0; et < 2; ++et)
#pragma unroll
        for (int ct = 0; ct < 4; ++ct)
#pragma unroll
            for (int r = 0; r < 4; ++r) {
                int row = w * 32 + et * 16 + lq * 4 + r;
                int col = ct * 16 + lr;
                eds[row * 64 + col] = f2bf(fmaxf(acc[et][ct][r], 0.f));
            }
    __syncthreads();
    for (int j = t; j < 1024; j += 256) {
        int le = j >> 3, q = j & 7;
        long e = eb + le;
        if (e < E)
            *(uint4*)(outb + e * 64 + q * 8) = *(const uint4*)&eds[le * 64 + q * 8];
    }
}

// ---------------------------------------------------------------------------
// edge_msg_lg: edges processed in dst-sorted (CSR-permuted) order.
// Block-local segmented reduction; plain store for complete segments,
// bf16-CAS only at block boundaries. outb must be pre-zeroed.
__global__ __launch_bounds__(256) void edge_msg_lg(
    const u16* __restrict__ feat, const int* __restrict__ ei,
    const float* __restrict__ attr, const float* __restrict__ W,
    const int* __restrict__ list, u16* __restrict__ outb, long E)
{
    __shared__ u16 inS[128 * 168];
    __shared__ u16 WS[64 * 168];
    __shared__ int dstS[128];
    __shared__ int idS[128];
    __shared__ int dprevS, dnextS;
    int t = threadIdx.x;
    long pb = (long)blockIdx.x * 128;
    for (int i = t; i < 64 * 144; i += 256) {
        int c = i / 144, k = i - c * 144;
        WS[c * 168 + k] = f2bf(W[i]);
    }
    for (int i = t; i < 64 * 24; i += 256) {
        int c = i / 24, k = 144 + (i - c * 24);
        WS[c * 168 + k] = 0;
    }
    if (t < 128) {
        long p = pb + t;
        int id = (p < E) ? list[p] : -1;
        idS[t] = id;
        dstS[t] = (id >= 0) ? ei[E + id] : -1;
    } else if (t == 128) {
        dprevS = (pb > 0) ? ei[E + list[pb - 1]] : -2;
    } else if (t == 129) {
        dnextS = (pb + 128 < E) ? ei[E + list[pb + 128]] : -2;
    }
    __syncthreads();
    {
        int le = t >> 1, half = t & 1;
        int id = idS[le];
        bool ok = (id >= 0);
        if (half == 0) {
            int src = ok ? ei[id] : 0;
            const uint4* sp = (const uint4*)(feat + (long)src * 64);
            u16* dp = &inS[le * 168];
#pragma unroll
            for (int j = 0; j < 8; ++j) {
                uint4 v = ok ? sp[j] : make_uint4(0, 0, 0, 0);
                *(uint4*)(dp + j * 8) = v;
            }
        } else {
            int dst = ok ? dstS[le] : 0;
            const uint4* sp = (const uint4*)(feat + (long)dst * 64);
            u16* dp = &inS[le * 168 + 64];
#pragma unroll
            for (int j = 0; j < 8; ++j) {
                uint4 v = ok ? sp[j] : make_uint4(0, 0, 0, 0);
                *(uint4*)(dp + j * 8) = v;
            }
            const float4* ap = (const float4*)(attr + (long)id * 16);
            u16* dq = &inS[le * 168 + 128];
#pragma unroll
            for (int j = 0; j < 4; ++j) {
                float4 v = ok ? ap[j] : make_float4(0.f, 0.f, 0.f, 0.f);
                dq[j * 4 + 0] = f2bf(v.x); dq[j * 4 + 1] = f2bf(v.y);
                dq[j * 4 + 2] = f2bf(v.z); dq[j * 4 + 3] = f2bf(v.w);
            }
            u16* dz = &inS[le * 168 + 144];
#pragma unroll
            for (int j = 0; j < 3; ++j) *(uint4*)(dz + j * 8) = make_uint4(0, 0, 0, 0);
        }
    }
    __syncthreads();
    int l = t & 63, w = t >> 6, lr = l & 15, lq = l >> 4;
    f32x4 acc[2][4];
#pragma unroll
    for (int et = 0; et < 2; ++et)
#pragma unroll
        for (int ct = 0; ct < 4; ++ct) acc[et][ct] = (f32x4){0.f, 0.f, 0.f, 0.f};
#pragma unroll
    for (int kc = 0; kc < 160; kc += 32) {
        bf16x8 a0 = *(const bf16x8*)&inS[(w * 32 + lr) * 168 + kc + lq * 8];
        bf16x8 a1 = *(const bf16x8*)&inS[(w * 32 + 16 + lr) * 168 + kc + lq * 8];
#pragma unroll
        for (int ct = 0; ct < 4; ++ct) {
            bf16x8 b = *(const bf16x8*)&WS[(ct * 16 + lr) * 168 + kc + lq * 8];
            acc[0][ct] = MFMA(a0, b, acc[0][ct]);
            acc[1][ct] = MFMA(a1, b, acc[1][ct]);
        }
    }
    __syncthreads();
    u16* eds = inS;
#pragma unroll
    for (int et = 0; et < 2; ++et)
#pragma unroll
        for (int ct = 0; ct < 4; ++ct)
#pragma unroll
            for (int r = 0; r < 4; ++r) {
                int row = w * 32 + et * 16 + lq * 4 + r;
                int col = ct * 16 + lr;
                eds[row * 64 + col] = f2bf(fmaxf(acc[et][ct][r], 0.f));
            }
    __syncthreads();
    for (int j = t; j < 4096; j += 256) {
        int le = j >> 5, wd = j & 31;
        int d = dstS[le];
        if (d < 0) continue;
        if (le > 0 && dstS[le - 1] == d) continue;  // not segment start
        float lo = 0.f, hi = 0.f;
        int le2 = le;
        do {
            u32 pair = *(const u32*)&eds[le2 * 64 + wd * 2];
            lo += bf2f((u16)(pair & 0xFFFFu));
            hi += bf2f((u16)(pair >> 16));
            ++le2;
        } while (le2 < 128 && dstS[le2] == d);
        bool bprev = (le == 0 && dprevS == d);
        bool bnext = (le2 == 128 && dnextS == d);
        u32* dw = (u32*)(outb + (long)d * 64 + wd * 2);
        if (bprev || bnext) {
            casAddPair(dw, lo, hi);
        } else {
            *dw = (u32)f2bf(lo) | ((u32)f2bf(hi) << 16);
        }
    }
}

// ---------------------------------------------------------------------------
// gather_g: aggB[n] = sum over CSR bucket of bf16 msg rows (one wave/node).
__global__ __launch_bounds__(256) void gather_g(
    const u16* __restrict__ m, const int* __restrict__ list,
    const u32* __restrict__ offc, u16* __restrict__ aggB,
    float* __restrict__ degOut, int N)
{
    int t = threadIdx.x, w = t >> 6, l = t & 63;
    long n = (long)blockIdx.x * 4 + w;
    if (n >= N) return;
    u32 start = n ? offc[n - 1] : 0u;
    u32 end = offc[n];
    float s = 0.f;
    for (u32 i = start; i < end; ++i) {
        int e = list[i];
        s += bf2f(m[(long)e * 64 + l]);
    }
    aggB[n * 64 + l] = f2bf(s);
    if (degOut && l == 0) degOut[n] = (float)(end - start);
}

// ---------------------------------------------------------------------------
// lstm2: bidirectional JK-LSTM, weights register-resident.
// 512 threads = 8 waves; wave w owns hidden units [16w,16w+16) for all 4 gate
// types. Whh slice (16 frags) + Wih slice (8 frags) loaded ONCE per block into
// VGPRs; block grid-strides over 32-node tiles. dir = blockIdx.y.
__global__ __launch_bounds__(512, 2) void lstm2(
    const u16* __restrict__ jkB, const u16* __restrict__ WhhB,
    const u16* __restrict__ WihB, const float* __restrict__ BS,
    const float* __restrict__ Watt, float* __restrict__ scores,
    int N, int ntiles)
{
    __shared__ u16 hS[32 * 136];
    __shared__ u16 xS[32 * 72];
    __shared__ float WattS[128];
    __shared__ float part[32 * 16];
    int t = threadIdx.x;
    int dir = blockIdx.y;
    int w = t >> 6, l = t & 63, lr = l & 15, lq = l >> 4;
    const u16* WhhD = WhhB + (long)dir * 65536;
    const u16* WihD = WihB + (long)dir * 32768;
    int grow = w * 16 + lr;               // unit index within [0,128)
    bf16x8 Wh[4][4], Wi[4][2];
    float bs[4];
#pragma unroll
    for (int ty = 0; ty < 4; ++ty) {
        int g = ty * 128 + grow;          // gate row within [0,512)
#pragma unroll
        for (int kc = 0; kc < 4; ++kc)
            Wh[ty][kc] = *(const bf16x8*)&WhhD[g * 128 + kc * 32 + lq * 8];
#pragma unroll
        for (int kc = 0; kc < 2; ++kc)
            Wi[ty][kc] = *(const bf16x8*)&WihD[g * 64 + kc * 32 + lq * 8];
        bs[ty] = BS[dir * 512 + g];
    }
    if (t < 128) WattS[t] = Watt[dir * 128 + t];
    float* scOut = scores + (long)dir * N * 4;

    for (int tile = blockIdx.x; tile < ntiles; tile += gridDim.x) {
        long n0 = (long)tile * 32;
        __syncthreads();                        // prev tile's hS reads done
        for (int i = t; i < 32 * 136; i += 512) hS[i] = 0;
        float creg[2][4] = {};
#pragma unroll 1
        for (int s = 0; s < 4; ++s) {
            int tt = dir ? (3 - s) : s;
            if (t < 256) {                      // stage x_t (32 nodes x 64)
                int n = t >> 3, j = t & 7;
                long gn = n0 + n;
                uint4 v = make_uint4(0, 0, 0, 0);
                if (gn < N) v = *(const uint4*)&jkB[((long)tt * N + gn) * 64 + j * 8];
                *(uint4*)&xS[n * 72 + j * 8] = v;
            }
            __syncthreads();                    // hS zero/write + xS visible
            f32x4 acc[4][2];
#pragma unroll
            for (int ty = 0; ty < 4; ++ty)
#pragma unroll
                for (int nt = 0; nt < 2; ++nt) {
                    float b0 = bs[ty];
                    acc[ty][nt] = (f32x4){b0, b0, b0, b0};
                }
#pragma unroll
            for (int kc = 0; kc < 4; ++kc) {
                bf16x8 a0 = *(const bf16x8*)&hS[lr * 136 + kc * 32 + lq * 8];
                bf16x8 a1 = *(const bf16x8*)&hS[(16 + lr) * 136 + kc * 32 + lq * 8];
#pragma unroll
                for (int ty = 0; ty < 4; ++ty) {
                    acc[ty][0] = MFMA(a0, Wh[ty][kc], acc[ty][0]);
                    acc[ty][1] = MFMA(a1, Wh[ty][kc], acc[ty][1]);
                }
            }
#pragma unroll
            for (int kc = 0; kc < 2; ++kc) {
                bf16x8 a0 = *(const bf16x8*)&xS[lr * 72 + kc * 32 + lq * 8];
                bf16x8 a1 = *(const bf16x8*)&xS[(16 + lr) * 72 + kc * 32 + lq * 8];
#pragma unroll
                for (int ty = 0; ty < 4; ++ty) {
                    acc[ty][0] = MFMA(a0, Wi[ty][kc], acc[ty][0]);
                    acc[ty][1] = MFMA(a1, Wi[ty][kc], acc[ty][1]);
                }
            }
            __syncthreads();                    // all hS reads done
#pragma unroll
            for (int nt = 0; nt < 2; ++nt)
#pragma unroll
                for (int r = 0; r < 4; ++r) {
                    float iv = acc[0][nt][r], fv = acc[1][nt][r];
                    float gv = acc[2][nt][r], ov = acc[3][nt][r];
                    float c = creg[nt][r];
                    float si = 1.f / (1.f + __expf(-iv));
                    float sf = 1.f / (1.f + __expf(-fv));
                    float tg = 2.f / (1.f + __expf(-2.f * gv)) - 1.f;
                    c = sf * c + si * tg;
                    float so = 1.f / (1.f + __expf(-ov));
                    float th = 2.f / (1.f + __expf(-2.f * c)) - 1.f;
                    creg[nt][r] = c;
                    int node = nt * 16 + lq * 4 + r;
                    hS[node * 136 + grow] = f2bf(so * th);
                }
            __syncthreads();                    // new h visible
            {
                int n = t & 31, ck = t >> 5;    // ck in [0,16)
                float sum = 0.f;
#pragma unroll
                for (int j = 0; j < 8; ++j)
                    sum += bf2f(hS[n * 136 + ck * 8 + j]) * WattS[ck * 8 + j];
                part[n * 16 + ck] = sum;
            }
            __syncthreads();
            if (t < 32) {
                long gn = n0 + t;
                if (gn < N) {
                    float v = 0.f;
#pragma unroll
                    for (int j = 0; j < 16; ++j) v += part[t * 16 + j];
                    scOut[gn * 4 + tt] = v;
                }
            }
        }
    }
}

// ---------------------------------------------------------------------------
__global__ __launch_bounds__(256) void final_kernel(
    const u16* __restrict__ jkB, const float* __restrict__ scores,
    const float* __restrict__ Wout, float* __restrict__ out, int N)
{
    __shared__ float feS[4][64];
    int t = threadIdx.x, l = t & 63, w = t >> 6;
    long n = (long)blockIdx.x * 4 + w;
    bool ok = (n < N);
    long nn = ok ? n : (long)(N - 1);
    float sc[4];
#pragma unroll
    for (int tt = 0; tt < 4; ++tt)
        sc[tt] = scores[nn * 4 + tt] + scores[(long)N * 4 + nn * 4 + tt];
    float m = fmaxf(fmaxf(sc[0], sc[1]), fmaxf(sc[2], sc[3]));
    float e0 = __expf(sc[0] - m), e1 = __expf(sc[1] - m);
    float e2 = __expf(sc[2] - m), e3 = __expf(sc[3] - m);
    float den = e0 + e1 + e2 + e3;
    float a0 = e0 / den, a1 = e1 / den, a2 = e2 / den, a3 = e3 / den;
    float fe = a0 * bf2f(jkB[nn * 64 + l]) + a1 * bf2f(jkB[((long)N + nn) * 64 + l]) +
               a2 * bf2f(jkB[((long)2 * N + nn) * 64 + l]) +
               a3 * bf2f(jkB[((long)3 * N + nn) * 64 + l]);
    feS[w][l] = fe;
    __syncthreads();
    float logit = 0.f;
    if (l < 40)
        for (int c = 0; c < 64; ++c) logit += feS[w][c] * Wout[l * 64 + c];
    float v = (l < 40) ? logit : -1e30f;
    for (int off = 32; off; off >>= 1) v = fmaxf(v, __shfl_xor(v, off));
    float ex = (l < 40) ? __expf(logit - v) : 0.f;
    for (int off = 32; off; off >>= 1) ex += __shfl_xor(ex, off);
    if (ok && l < 40) out[n * 40 + l] = logit - v - __logf(ex);
}

// ---------------------------------------------------------------------------
extern "C" void kernel_launch(void* const* d_in, const int* in_sizes, int n_in,
                              void* d_out, int out_size, void* d_ws, size_t ws_size,
                              hipStream_t stream)
{
    const float* x        = (const float*)d_in[0];
    const int*   eig      = (const int*)d_in[1];
    const float* eag      = (const float*)d_in[2];
    const int*   eilg     = (const int*)d_in[3];
    const float* ealg     = (const float*)d_in[4];
    const float* W_feat   = (const float*)d_in[5];
    const float* W_msg    = (const float*)d_in[6];
    const float* W_lg2g   = (const float*)d_in[7];
    const float* b_lg2g   = (const float*)d_in[8];
    const float* W_msg_l  = (const float*)d_in[9];
    const float* Wih_f    = (const float*)d_in[10];
    const float* Whh_f    = (const float*)d_in[11];
    const float* bih_f    = (const float*)d_in[12];
    const float* bhh_f    = (const float*)d_in[13];
    const float* Wih_b    = (const float*)d_in[14];
    const float* Whh_b    = (const float*)d_in[15];
    const float* bih_b    = (const float*)d_in[16];
    const float* bhh_b    = (const float*)d_in[17];
    const float* W_att    = (const float*)d_in[18];
    const float* W_out    = (const float*)d_in[20];

    int  N   = in_sizes[0] / 128;
    long Eg  = in_sizes[1] / 2;
    long Elg = in_sizes[3] / 2;

    char* wp = (char*)d_ws;
    auto alloc = [&](size_t bytes) -> char* {
        char* p = wp; wp += (bytes + 255) & ~(size_t)255; return p;
    };
    u16*   jkB    = (u16*)  alloc((size_t)4 * N * 64 * 2);
    u16*   mA     = (u16*)  alloc((size_t)Eg * 64 * 2);
    u16*   mB     = (u16*)  alloc((size_t)Eg * 64 * 2);
    u16*   aggB   = (u16*)  alloc((size_t)N * 64 * 2);
    float* deg    = (float*)alloc((size_t)N * 4);
    float* scores = (float*)alloc((size_t)2 * N * 4 * 4);
    u16*   WhhB   = (u16*)  alloc((size_t)2 * 65536 * 2);
    u16*   WihB   = (u16*)  alloc((size_t)2 * 32768 * 2);
    float* BS     = (float*)alloc((size_t)2 * 512 * 4);
    u32*   off_g  = (u32*)  alloc((size_t)(N + 1) * 4);
    int*   list_g = (int*)  alloc((size_t)Eg * 4);
    u32*   off_lg = (u32*)  alloc((size_t)(Eg + 1) * 4);
    int*   list_lg= (int*)  alloc((size_t)Elg * 4);
    u32*   part   = (u32*)  alloc((size_t)1024 * 4);

    prep_w<<<772, 256, 0, stream>>>(Whh_f, Whh_b, Wih_f, Wih_b,
                                    bih_f, bhh_f, bih_b, bhh_b, WhhB, WihB, BS);
    // ---- CSR build: g-graph (dst over nodes) ----
    hipMemsetAsync(off_g, 0, (size_t)(N + 1) * 4, stream);
    count_kernel<<<(int)((Eg + 255) / 256), 256, 0, stream>>>(eig + Eg, off_g, Eg);
    {
        int nb = (N + 1023) / 1024;
        scan1<<<nb, 256, 0, stream>>>(off_g, part, N);
        scan2<<<1, 1024, 0, stream>>>(part, nb, off_g + N);
        scan3<<<nb, 256, 0, stream>>>(off_g, part, N);
    }
    fill_kernel<<<(int)((Eg + 255) / 256), 256, 0, stream>>>(eig + Eg, off_g, list_g, Eg);
    // ---- CSR build: lg-graph (dst over g-edges) ----
    hipMemsetAsync(off_lg, 0, (size_t)(Eg + 1) * 4, stream);
    count_kernel<<<(int)((Elg + 255) / 256), 256, 0, stream>>>(eilg + Elg, off_lg, Elg);
    {
        int nb = (int)((Eg + 1023) / 1024);
        scan1<<<nb, 256, 0, stream>>>(off_lg, part, (int)Eg);
        scan2<<<1, 1024, 0, stream>>>(part, nb, off_lg + Eg);
        scan3<<<nb, 256, 0, stream>>>(off_lg, part, (int)Eg);
    }
    fill_kernel<<<(int)((Elg + 255) / 256), 256, 0, stream>>>(eilg + Elg, off_lg, list_lg, Elg);

    // jk0 = relu(x @ W_feat^T)
    rowgemm<128, true, false><<<(N + 63) / 64, 256, 0, stream>>>(
        x, W_feat, nullptr, nullptr, jkB, N);
    // initial msgs -> mA (plain stores)
    edge_msg_init<<<(int)((Eg + 127) / 128), 256, 0, stream>>>(
        jkB, eig, eag, W_msg, mA, Eg);
    // jk1 = gather(mA) @ W_lg2g^T + deg*b
    gather_g<<<(N + 3) / 4, 256, 0, stream>>>(mA, list_g, off_g, aggB, deg, N);
    rowgemm<64, false, true><<<(N + 63) / 64, 256, 0, stream>>>(
        aggB, W_lg2g, b_lg2g, deg, jkB + (size_t)N * 64, N);
    // ---- linegraph layer 0: mA -> mB ----
    hipMemsetAsync(mB, 0, (size_t)Eg * 64 * 2, stream);
    edge_msg_lg<<<(int)((Elg + 127) / 128), 256, 0, stream>>>(
        mA, eilg, ealg, W_msg_l, list_lg, mB, Elg);
    gather_g<<<(N + 3) / 4, 256, 0, stream>>>(mB, list_g, off_g, aggB, nullptr, N);
    rowgemm<64, false, true><<<(N + 63) / 64, 256, 0, stream>>>(
        aggB, W_lg2g, b_lg2g, nullptr, jkB + (size_t)2 * N * 64, N);
    // ---- linegraph layer 1: mB -> mA ----
    hipMemsetAsync(mA, 0, (size_t)Eg * 64 * 2, stream);
    edge_msg_lg<<<(int)((Elg + 127) / 128), 256, 0, stream>>>(
        mB, eilg, ealg, W_msg_l + 64 * 144, list_lg, mA, Elg);
    gather_g<<<(N + 3) / 4, 256, 0, stream>>>(mA, list_g, off_g, aggB, nullptr, N);
    rowgemm<64, false, true><<<(N + 63) / 64, 256, 0, stream>>>(
        aggB, W_lg2g, b_lg2g, nullptr, jkB + (size_t)3 * N * 64, N);
    // ---- JK bidirectional LSTM (register-resident weights) ----
    {
        int ntiles = (N + 31) / 32;
        lstm2<<<dim3(128, 2), 512, 0, stream>>>(
            jkB, WhhB, WihB, BS, W_att, scores, N, ntiles);
    }
    final_kernel<<<(N + 3) / 4, 256, 0, stream>>>(
        jkB, scores, W_out, (float*)d_out, N);
}

// Round 5
// 1348.930 us; speedup vs baseline: 2.4559x; 1.1022x over previous
//
#include <hip/hip_runtime.h>

typedef unsigned short u16;
typedef unsigned int u32;
typedef __attribute__((ext_vector_type(8))) short bf16x8;
typedef __attribute__((ext_vector_type(4))) float f32x4;

#define MFMA(a, b, c) __builtin_amdgcn_mfma_f32_16x16x32_bf16(a, b, c, 0, 0, 0)

__device__ __forceinline__ u16 f2bf(float x) {
    union { float f; u32 u; } v; v.f = x;
    u32 r = (v.u + 0x7FFFu + ((v.u >> 16) & 1u)) >> 16;
    return (u16)r;
}
__device__ __forceinline__ float bf2f(u16 b) {
    union { u32 u; float f; } v; v.u = ((u32)b) << 16;
    return v.f;
}
__device__ __forceinline__ void casAddPair(u32* w, float lo, float hi) {
    u32 old = *w, assumed;
    do {
        assumed = old;
        u32 des = (u32)f2bf(bf2f((u16)(assumed & 0xFFFFu)) + lo) |
                  ((u32)f2bf(bf2f((u16)(assumed >> 16)) + hi) << 16);
        if (des == assumed) break;
        old = atomicCAS(w, assumed, des);
    } while (old != assumed);
}

// ---------------------------------------------------------------------------
// prep: convert LSTM weights to bf16, combine biases
__global__ __launch_bounds__(256) void prep_w(
    const float* __restrict__ Whh_f, const float* __restrict__ Whh_b,
    const float* __restrict__ Wih_f, const float* __restrict__ Wih_b,
    const float* __restrict__ bih_f, const float* __restrict__ bhh_f,
    const float* __restrict__ bih_b, const float* __restrict__ bhh_b,
    u16* __restrict__ WhhB, u16* __restrict__ WihB, float* __restrict__ BS)
{
    int i = blockIdx.x * 256 + threadIdx.x;
    if (i < 131072) {
        int d = i >> 16, r = i & 65535;
        WhhB[i] = f2bf(d ? Whh_b[r] : Whh_f[r]);
    } else if (i < 196608) {
        int i2 = i - 131072; int d = i2 >> 15, r = i2 & 32767;
        WihB[i2] = f2bf(d ? Wih_b[r] : Wih_f[r]);
    } else if (i < 197632) {
        int i3 = i - 196608; int d = i3 >> 9, g = i3 & 511;
        BS[i3] = d ? (bih_b[g] + bhh_b[g]) : (bih_f[g] + bhh_f[g]);
    }
}

// ---------------------------------------------------------------------------
// CSR build: count -> 3-phase exclusive scan -> fill (fill corrupts offsets
// into end-offsets; gather uses off[n-1]..off[n] with off[-1]=0).
__global__ __launch_bounds__(256) void count_kernel(const int* __restrict__ dst,
                                                    u32* __restrict__ cnt, long E)
{
    long i = (long)blockIdx.x * 256 + threadIdx.x;
    if (i < E) atomicAdd(&cnt[dst[i]], 1u);
}

__global__ __launch_bounds__(256) void scan1(const u32* __restrict__ a,
                                             u32* __restrict__ part, int n)
{
    __shared__ u32 ts[256];
    int b = blockIdx.x, t = threadIdx.x;
    long i0 = (long)b * 1024 + t * 4;
    u32 s = 0;
#pragma unroll
    for (int k = 0; k < 4; ++k) { long i = i0 + k; if (i < n) s += a[i]; }
    ts[t] = s; __syncthreads();
    for (int off = 1; off < 256; off <<= 1) {
        u32 x = (t >= off) ? ts[t - off] : 0u;
        __syncthreads(); ts[t] += x; __syncthreads();
    }
    if (t == 255) part[b] = ts[255];
}

__global__ __launch_bounds__(1024) void scan2(u32* __restrict__ part, int nb,
                                              u32* __restrict__ total_out)
{
    __shared__ u32 ts[1024];
    int t = threadIdx.x;
    u32 v = (t < nb) ? part[t] : 0u;
    ts[t] = v; __syncthreads();
    for (int off = 1; off < 1024; off <<= 1) {
        u32 x = (t >= off) ? ts[t - off] : 0u;
        __syncthreads(); ts[t] += x; __syncthreads();
    }
    if (t < nb) part[t] = ts[t] - v;
    if (t == 1023 && total_out) *total_out = ts[1023];
}

__global__ __launch_bounds__(256) void scan3(u32* __restrict__ a,
                                             const u32* __restrict__ part, int n)
{
    __shared__ u32 ts[256];
    int b = blockIdx.x, t = threadIdx.x;
    long i0 = (long)b * 1024 + t * 4;
    u32 v[4]; u32 s = 0;
#pragma unroll
    for (int k = 0; k < 4; ++k) { long i = i0 + k; v[k] = (i < n) ? a[i] : 0u; s += v[k]; }
    ts[t] = s; __syncthreads();
    for (int off = 1; off < 256; off <<= 1) {
        u32 x = (t >= off) ? ts[t - off] : 0u;
        __syncthreads(); ts[t] += x; __syncthreads();
    }
    u32 run = part[b] + ts[t] - s;
#pragma unroll
    for (int k = 0; k < 4; ++k) {
        long i = i0 + k;
        if (i < n) { u32 x = v[k]; a[i] = run; run += x; }
    }
}

__global__ __launch_bounds__(256) void fill_kernel(const int* __restrict__ dst,
                                                   u32* __restrict__ off,
                                                   int* __restrict__ list, long E)
{
    long i = (long)blockIdx.x * 256 + threadIdx.x;
    if (i < E) {
        u32 pos = atomicAdd(&off[dst[i]], 1u);
        list[pos] = (int)i;
    }
}

// ---------------------------------------------------------------------------
// rowgemm: outb[M x 64] (bf16) = act(in[M x K] @ W[64 x K]^T (+ bias*scale))
template <int K, bool RELU, bool INBF16>
__global__ __launch_bounds__(256) void rowgemm(
    const void* __restrict__ in, const float* __restrict__ W,
    const float* __restrict__ bias, const float* __restrict__ bias_scale,
    u16* __restrict__ outb, int M)
{
    constexpr int KP = K + 8;
    __shared__ u16 inS[64 * KP];
    __shared__ u16 WS[64 * KP];
    int t = threadIdx.x;
    long rb = (long)blockIdx.x * 64;
    for (int i = t; i < 64 * K; i += 256) {
        int c = i / K, k = i - c * K;
        WS[c * KP + k] = f2bf(W[i]);
    }
    if (INBF16) {
        const u16* inb = (const u16*)in;
        for (int i = t; i < 64 * K / 8; i += 256) {
            int r = i / (K / 8), q = i - r * (K / 8);
            long gr = rb + r;
            uint4 v = make_uint4(0, 0, 0, 0);
            if (gr < M) v = *(const uint4*)&inb[gr * (long)K + q * 8];
            *(uint4*)&inS[r * KP + q * 8] = v;
        }
    } else {
        const float* inf = (const float*)in;
        for (int i = t; i < 64 * K; i += 256) {
            int r = i / K, k = i - r * K;
            long gr = rb + r;
            inS[r * KP + k] = (gr < M) ? f2bf(inf[gr * (long)K + k]) : (u16)0;
        }
    }
    __syncthreads();
    int l = t & 63, w = t >> 6, lr = l & 15, lq = l >> 4;
    f32x4 acc[4];
#pragma unroll
    for (int i = 0; i < 4; ++i) acc[i] = (f32x4){0.f, 0.f, 0.f, 0.f};
#pragma unroll
    for (int kc = 0; kc < K; kc += 32) {
        bf16x8 a = *(const bf16x8*)&inS[(w * 16 + lr) * KP + kc + lq * 8];
#pragma unroll
        for (int ct = 0; ct < 4; ++ct) {
            bf16x8 b = *(const bf16x8*)&WS[(ct * 16 + lr) * KP + kc + lq * 8];
            acc[ct] = MFMA(a, b, acc[ct]);
        }
    }
#pragma unroll
    for (int ct = 0; ct < 4; ++ct)
#pragma unroll
        for (int r = 0; r < 4; ++r) {
            long gr = rb + w * 16 + lq * 4 + r;
            if (gr < M) {
                int c = ct * 16 + lr;
                float v = acc[ct][r];
                if (bias) v += bias[c] * (bias_scale ? bias_scale[gr] : 1.f);
                if (RELU) v = fmaxf(v, 0.f);
                outb[gr * 64 + c] = f2bf(v);
            }
        }
}

// ---------------------------------------------------------------------------
// edge_msg_init: 512 threads, 128 edges/block. Natural order, plain stores.
__global__ __launch_bounds__(512) void edge_msg_init(
    const u16* __restrict__ feat, const int* __restrict__ ei,
    const float* __restrict__ attr, const float* __restrict__ W,
    u16* __restrict__ outb, long E)
{
    __shared__ u16 inS[128 * 168];
    __shared__ u16 WS[64 * 168];
    int t = threadIdx.x;
    long eb = (long)blockIdx.x * 128;
    for (int i = t; i < 64 * 144; i += 512) {
        int c = i / 144, k = i - c * 144;
        WS[c * 168 + k] = f2bf(W[i]);
    }
    for (int i = t; i < 64 * 24; i += 512) {
        int c = i / 24, k = 144 + (i - c * 24);
        WS[c * 168 + k] = 0;
    }
    {
        int le = t >> 2, q = t & 3;
        long e = eb + le;
        bool ok = (e < E);
        int src = ok ? ei[e] : 0;
        int dst = ok ? ei[E + e] : 0;
        u16* dp = &inS[le * 168];
        const uint4* sp = (const uint4*)(feat + (long)src * 64);
        const uint4* dpg = (const uint4*)(feat + (long)dst * 64);
#pragma unroll
        for (int j = q; j < 21; j += 4) {
            uint4 v = make_uint4(0, 0, 0, 0);
            int off;
            if (j < 8) { if (ok) v = sp[j]; off = j * 8; }
            else if (j < 16) { if (ok) v = dpg[j - 8]; off = 64 + (j - 8) * 8; }
            else if (j < 18) {
                if (ok) {
                    const float4* ap = (const float4*)(attr + e * 16) + (j - 16) * 2;
                    float4 a0 = ap[0], a1 = ap[1];
                    v.x = (u32)f2bf(a0.x) | ((u32)f2bf(a0.y) << 16);
                    v.y = (u32)f2bf(a0.z) | ((u32)f2bf(a0.w) << 16);
                    v.z = (u32)f2bf(a1.x) | ((u32)f2bf(a1.y) << 16);
                    v.w = (u32)f2bf(a1.z) | ((u32)f2bf(a1.w) << 16);
                }
                off = 128 + (j - 16) * 8;
            } else { off = 144 + (j - 18) * 8; }
            *(uint4*)(dp + off) = v;
        }
    }
    __syncthreads();
    int w = t >> 6, l = t & 63, lr = l & 15, lq = l >> 4;
    f32x4 acc[4];
#pragma unroll
    for (int ct = 0; ct < 4; ++ct) acc[ct] = (f32x4){0.f, 0.f, 0.f, 0.f};
#pragma unroll
    for (int kc = 0; kc < 160; kc += 32) {
        bf16x8 a = *(const bf16x8*)&inS[(w * 16 + lr) * 168 + kc + lq * 8];
#pragma unroll
        for (int ct = 0; ct < 4; ++ct) {
            bf16x8 b = *(const bf16x8*)&WS[(ct * 16 + lr) * 168 + kc + lq * 8];
            acc[ct] = MFMA(a, b, acc[ct]);
        }
    }
    __syncthreads();
    u16* eds = inS;
#pragma unroll
    for (int ct = 0; ct < 4; ++ct)
#pragma unroll
        for (int r = 0; r < 4; ++r) {
            int row = w * 16 + lq * 4 + r;
            int col = ct * 16 + lr;
            eds[row * 64 + col] = f2bf(fmaxf(acc[ct][r], 0.f));
        }
    __syncthreads();
    for (int j = t; j < 1024; j += 512) {
        int le = j >> 3, q = j & 7;
        long e = eb + le;
        if (e < E)
            *(uint4*)(outb + e * 64 + q * 8) = *(const uint4*)&eds[le * 64 + q * 8];
    }
}

// ---------------------------------------------------------------------------
// edge_msg_lg: 512 threads, 128 edges/block, dst-sorted (CSR-permuted) order.
// Block-local segmented reduction; bf16-CAS only at block boundaries.
__global__ __launch_bounds__(512) void edge_msg_lg(
    const u16* __restrict__ feat, const int* __restrict__ ei,
    const float* __restrict__ attr, const float* __restrict__ W,
    const int* __restrict__ list, u16* __restrict__ outb, long E)
{
    __shared__ u16 inS[128 * 168];
    __shared__ u16 WS[64 * 168];
    __shared__ int dstS[128];
    __shared__ int idS[128];
    __shared__ int dprevS, dnextS;
    int t = threadIdx.x;
    long pb = (long)blockIdx.x * 128;
    for (int i = t; i < 64 * 144; i += 512) {
        int c = i / 144, k = i - c * 144;
        WS[c * 168 + k] = f2bf(W[i]);
    }
    for (int i = t; i < 64 * 24; i += 512) {
        int c = i / 24, k = 144 + (i - c * 24);
        WS[c * 168 + k] = 0;
    }
    if (t < 128) {
        long p = pb + t;
        int id = (p < E) ? list[p] : -1;
        idS[t] = id;
        dstS[t] = (id >= 0) ? ei[E + id] : -1;
    } else if (t == 128) {
        dprevS = (pb > 0) ? ei[E + list[pb - 1]] : -2;
    } else if (t == 129) {
        dnextS = (pb + 128 < E) ? ei[E + list[pb + 128]] : -2;
    }
    __syncthreads();
    {
        int le = t >> 2, q = t & 3;
        int id = idS[le];
        bool ok = (id >= 0);
        int src = ok ? ei[id] : 0;
        int dst = ok ? dstS[le] : 0;
        u16* dp = &inS[le * 168];
        const uint4* sp = (const uint4*)(feat + (long)src * 64);
        const uint4* dpg = (const uint4*)(feat + (long)dst * 64);
#pragma unroll
        for (int j = q; j < 21; j += 4) {
            uint4 v = make_uint4(0, 0, 0, 0);
            int off;
            if (j < 8) { if (ok) v = sp[j]; off = j * 8; }
            else if (j < 16) { if (ok) v = dpg[j - 8]; off = 64 + (j - 8) * 8; }
            else if (j < 18) {
                if (ok) {
                    const float4* ap = (const float4*)(attr + (long)id * 16) + (j - 16) * 2;
                    float4 a0 = ap[0], a1 = ap[1];
                    v.x = (u32)f2bf(a0.x) | ((u32)f2bf(a0.y) << 16);
                    v.y = (u32)f2bf(a0.z) | ((u32)f2bf(a0.w) << 16);
                    v.z = (u32)f2bf(a1.x) | ((u32)f2bf(a1.y) << 16);
                    v.w = (u32)f2bf(a1.z) | ((u32)f2bf(a1.w) << 16);
                }
                off = 128 + (j - 16) * 8;
            } else { off = 144 + (j - 18) * 8; }
            *(uint4*)(dp + off) = v;
        }
    }
    __syncthreads();
    int w = t >> 6, l = t & 63, lr = l & 15, lq = l >> 4;
    f32x4 acc[4];
#pragma unroll
    for (int ct = 0; ct < 4; ++ct) acc[ct] = (f32x4){0.f, 0.f, 0.f, 0.f};
#pragma unroll
    for (int kc = 0; kc < 160; kc += 32) {
        bf16x8 a = *(const bf16x8*)&inS[(w * 16 + lr) * 168 + kc + lq * 8];
#pragma unroll
        for (int ct = 0; ct < 4; ++ct) {
            bf16x8 b = *(const bf16x8*)&WS[(ct * 16 + lr) * 168 + kc + lq * 8];
            acc[ct] = MFMA(a, b, acc[ct]);
        }
    }
    __syncthreads();
    u16* eds = inS;
#pragma unroll
    for (int ct = 0; ct < 4; ++ct)
#pragma unroll
        for (int r = 0; r < 4; ++r) {
            int row = w * 16 + lq * 4 + r;
            int col = ct * 16 + lr;
            eds[row * 64 + col] = f2bf(fmaxf(acc[ct][r], 0.f));
        }
    __syncthreads();
    for (int j = t; j < 4096; j += 512) {
        int le = j >> 5, wd = j & 31;
        int d = dstS[le];
        if (d < 0) continue;
        if (le > 0 && dstS[le - 1] == d) continue;  // not segment start
        float lo = 0.f, hi = 0.f;
        int le2 = le;
        do {
            u32 pair = *(const u32*)&eds[le2 * 64 + wd * 2];
            lo += bf2f((u16)(pair & 0xFFFFu));
            hi += bf2f((u16)(pair >> 16));
            ++le2;
        } while (le2 < 128 && dstS[le2] == d);
        bool bprev = (le == 0 && dprevS == d);
        bool bnext = (le2 == 128 && dnextS == d);
        u32* dw = (u32*)(outb + (long)d * 64 + wd * 2);
        if (bprev || bnext) {
            casAddPair(dw, lo, hi);
        } else {
            *dw = (u32)f2bf(lo) | ((u32)f2bf(hi) << 16);
        }
    }
}

// ---------------------------------------------------------------------------
// gather_g: aggB[n] = sum over CSR bucket of bf16 msg rows (one wave/node).
__global__ __launch_bounds__(256) void gather_g(
    const u16* __restrict__ m, const int* __restrict__ list,
    const u32* __restrict__ offc, u16* __restrict__ aggB,
    float* __restrict__ degOut, int N)
{
    int t = threadIdx.x, w = t >> 6, l = t & 63;
    long n = (long)blockIdx.x * 4 + w;
    if (n >= N) return;
    u32 start = n ? offc[n - 1] : 0u;
    u32 end = offc[n];
    float s = 0.f;
    for (u32 i = start; i < end; ++i) {
        int e = list[i];
        s += bf2f(m[(long)e * 64 + l]);
    }
    aggB[n * 64 + l] = f2bf(s);
    if (degOut && l == 0) degOut[n] = (float)(end - start);
}

// ---------------------------------------------------------------------------
// lstm2: bidirectional JK-LSTM, weights register-resident.
// 512 threads = 8 waves; wave w owns hidden units [16w,16w+16) for all 4 gate
// types. Whh slice (16 frags) + Wih slice (8 frags) loaded ONCE per block into
// VGPRs; block grid-strides over 32-node tiles. dir = blockIdx.y.
__global__ __launch_bounds__(512, 2) void lstm2(
    const u16* __restrict__ jkB, const u16* __restrict__ WhhB,
    const u16* __restrict__ WihB, const float* __restrict__ BS,
    const float* __restrict__ Watt, float* __restrict__ scores,
    int N, int ntiles)
{
    __shared__ u16 hS[32 * 136];
    __shared__ u16 xS[32 * 72];
    __shared__ float WattS[128];
    __shared__ float part[32 * 16];
    int t = threadIdx.x;
    int dir = blockIdx.y;
    int w = t >> 6, l = t & 63, lr = l & 15, lq = l >> 4;
    const u16* WhhD = WhhB + (long)dir * 65536;
    const u16* WihD = WihB + (long)dir * 32768;
    int grow = w * 16 + lr;               // unit index within [0,128)
    bf16x8 Wh[4][4], Wi[4][2];
    float bs[4];
#pragma unroll
    for (int ty = 0; ty < 4; ++ty) {
        int g = ty * 128 + grow;          // gate row within [0,512)
#pragma unroll
        for (int kc = 0; kc < 4; ++kc)
            Wh[ty][kc] = *(const bf16x8*)&WhhD[g * 128 + kc * 32 + lq * 8];
#pragma unroll
        for (int kc = 0; kc < 2; ++kc)
            Wi[ty][kc] = *(const bf16x8*)&WihD[g * 64 + kc * 32 + lq * 8];
        bs[ty] = BS[dir * 512 + g];
    }
    if (t < 128) WattS[t] = Watt[dir * 128 + t];
    float* scOut = scores + (long)dir * N * 4;

    for (int tile = blockIdx.x; tile < ntiles; tile += gridDim.x) {
        long n0 = (long)tile * 32;
        __syncthreads();                        // prev tile's hS reads done
        for (int i = t; i < 32 * 136; i += 512) hS[i] = 0;
        float creg[2][4] = {};
#pragma unroll 1
        for (int s = 0; s < 4; ++s) {
            int tt = dir ? (3 - s) : s;
            if (t < 256) {                      // stage x_t (32 nodes x 64)
                int n = t >> 3, j = t & 7;
                long gn = n0 + n;
                uint4 v = make_uint4(0, 0, 0, 0);
                if (gn < N) v = *(const uint4*)&jkB[((long)tt * N + gn) * 64 + j * 8];
                *(uint4*)&xS[n * 72 + j * 8] = v;
            }
            __syncthreads();                    // hS zero/write + xS visible
            f32x4 acc[4][2];
#pragma unroll
            for (int ty = 0; ty < 4; ++ty)
#pragma unroll
                for (int nt = 0; nt < 2; ++nt) {
                    float b0 = bs[ty];
                    acc[ty][nt] = (f32x4){b0, b0, b0, b0};
                }
#pragma unroll
            for (int kc = 0; kc < 4; ++kc) {
                bf16x8 a0 = *(const bf16x8*)&hS[lr * 136 + kc * 32 + lq * 8];
                bf16x8 a1 = *(const bf16x8*)&hS[(16 + lr) * 136 + kc * 32 + lq * 8];
#pragma unroll
                for (int ty = 0; ty < 4; ++ty) {
                    acc[ty][0] = MFMA(a0, Wh[ty][kc], acc[ty][0]);
                    acc[ty][1] = MFMA(a1, Wh[ty][kc], acc[ty][1]);
                }
            }
#pragma unroll
            for (int kc = 0; kc < 2; ++kc) {
                bf16x8 a0 = *(const bf16x8*)&xS[lr * 72 + kc * 32 + lq * 8];
                bf16x8 a1 = *(const bf16x8*)&xS[(16 + lr) * 72 + kc * 32 + lq * 8];
#pragma unroll
                for (int ty = 0; ty < 4; ++ty) {
                    acc[ty][0] = MFMA(a0, Wi[ty][kc], acc[ty][0]);
                    acc[ty][1] = MFMA(a1, Wi[ty][kc], acc[ty][1]);
                }
            }
            __syncthreads();                    // all hS reads done
#pragma unroll
            for (int nt = 0; nt < 2; ++nt)
#pragma unroll
                for (int r = 0; r < 4; ++r) {
                    float iv = acc[0][nt][r], fv = acc[1][nt][r];
                    float gv = acc[2][nt][r], ov = acc[3][nt][r];
                    float c = creg[nt][r];
                    float si = 1.f / (1.f + __expf(-iv));
                    float sf = 1.f / (1.f + __expf(-fv));
                    float tg = 2.f / (1.f + __expf(-2.f * gv)) - 1.f;
                    c = sf * c + si * tg;
                    float so = 1.f / (1.f + __expf(-ov));
                    float th = 2.f / (1.f + __expf(-2.f * c)) - 1.f;
                    creg[nt][r] = c;
                    int node = nt * 16 + lq * 4 + r;
                    hS[node * 136 + grow] = f2bf(so * th);
                }
            __syncthreads();                    // new h visible
            {
                int n = t & 31, ck = t >> 5;    // ck in [0,16)
                float sum = 0.f;
#pragma unroll
                for (int j = 0; j < 8; ++j)
                    sum += bf2f(hS[n * 136 + ck * 8 + j]) * WattS[ck * 8 + j];
                part[n * 16 + ck] = sum;
            }
            __syncthreads();
            if (t < 32) {
                long gn = n0 + t;
                if (gn < N) {
                    float v = 0.f;
#pragma unroll
                    for (int j = 0; j < 16; ++j) v += part[t * 16 + j];
                    scOut[gn * 4 + tt] = v;
                }
            }
        }
    }
}

// ---------------------------------------------------------------------------
__global__ __launch_bounds__(256) void final_kernel(
    const u16* __restrict__ jkB, const float* __restrict__ scores,
    const float* __restrict__ Wout, float* __restrict__ out, int N)
{
    __shared__ float feS[4][64];
    int t = threadIdx.x, l = t & 63, w = t >> 6;
    long n = (long)blockIdx.x * 4 + w;
    bool ok = (n < N);
    long nn = ok ? n : (long)(N - 1);
    float sc[4];
#pragma unroll
    for (int tt = 0; tt < 4; ++tt)
        sc[tt] = scores[nn * 4 + tt] + scores[(long)N * 4 + nn * 4 + tt];
    float m = fmaxf(fmaxf(sc[0], sc[1]), fmaxf(sc[2], sc[3]));
    float e0 = __expf(sc[0] - m), e1 = __expf(sc[1] - m);
    float e2 = __expf(sc[2] - m), e3 = __expf(sc[3] - m);
    float den = e0 + e1 + e2 + e3;
    float a0 = e0 / den, a1 = e1 / den, a2 = e2 / den, a3 = e3 / den;
    float fe = a0 * bf2f(jkB[nn * 64 + l]) + a1 * bf2f(jkB[((long)N + nn) * 64 + l]) +
               a2 * bf2f(jkB[((long)2 * N + nn) * 64 + l]) +
               a3 * bf2f(jkB[((long)3 * N + nn) * 64 + l]);
    feS[w][l] = fe;
    __syncthreads();
    float logit = 0.f;
    if (l < 40)
        for (int c = 0; c < 64; ++c) logit += feS[w][c] * Wout[l * 64 + c];
    float v = (l < 40) ? logit : -1e30f;
    for (int off = 32; off; off >>= 1) v = fmaxf(v, __shfl_xor(v, off));
    float ex = (l < 40) ? __expf(logit - v) : 0.f;
    for (int off = 32; off; off >>= 1) ex += __shfl_xor(ex, off);
    if (ok && l < 40) out[n * 40 + l] = logit - v - __logf(ex);
}

// ---------------------------------------------------------------------------
extern "C" void kernel_launch(void* const* d_in, const int* in_sizes, int n_in,
                              void* d_out, int out_size, void* d_ws, size_t ws_size,
                              hipStream_t stream)
{
    const float* x        = (const float*)d_in[0];
    const int*   eig      = (const int*)d_in[1];
    const float* eag      = (const float*)d_in[2];
    const int*   eilg     = (const int*)d_in[3];
    const float* ealg     = (const float*)d_in[4];
    const float* W_feat   = (const float*)d_in[5];
    const float* W_msg    = (const float*)d_in[6];
    const float* W_lg2g   = (const float*)d_in[7];
    const float* b_lg2g   = (const float*)d_in[8];
    const float* W_msg_l  = (const float*)d_in[9];
    const float* Wih_f    = (const float*)d_in[10];
    const float* Whh_f    = (const float*)d_in[11];
    const float* bih_f    = (const float*)d_in[12];
    const float* bhh_f    = (const float*)d_in[13];
    const float* Wih_b    = (const float*)d_in[14];
    const float* Whh_b    = (const float*)d_in[15];
    const float* bih_b    = (const float*)d_in[16];
    const float* bhh_b    = (const float*)d_in[17];
    const float* W_att    = (const float*)d_in[18];
    const float* W_out    = (const float*)d_in[20];

    int  N   = in_sizes[0] / 128;
    long Eg  = in_sizes[1] / 2;
    long Elg = in_sizes[3] / 2;

    char* wp = (char*)d_ws;
    auto alloc = [&](size_t bytes) -> char* {
        char* p = wp; wp += (bytes + 255) & ~(size_t)255; return p;
    };
    u16*   jkB    = (u16*)  alloc((size_t)4 * N * 64 * 2);
    u16*   mA     = (u16*)  alloc((size_t)Eg * 64 * 2);
    u16*   mB     = (u16*)  alloc((size_t)Eg * 64 * 2);
    u16*   aggB   = (u16*)  alloc((size_t)N * 64 * 2);
    float* deg    = (float*)alloc((size_t)N * 4);
    float* scores = (float*)alloc((size_t)2 * N * 4 * 4);
    u16*   WhhB   = (u16*)  alloc((size_t)2 * 65536 * 2);
    u16*   WihB   = (u16*)  alloc((size_t)2 * 32768 * 2);
    float* BS     = (float*)alloc((size_t)2 * 512 * 4);
    u32*   off_g  = (u32*)  alloc((size_t)(N + 1) * 4);
    int*   list_g = (int*)  alloc((size_t)Eg * 4);
    u32*   off_lg = (u32*)  alloc((size_t)(Eg + 1) * 4);
    int*   list_lg= (int*)  alloc((size_t)Elg * 4);
    u32*   part   = (u32*)  alloc((size_t)1024 * 4);

    prep_w<<<772, 256, 0, stream>>>(Whh_f, Whh_b, Wih_f, Wih_b,
                                    bih_f, bhh_f, bih_b, bhh_b, WhhB, WihB, BS);
    // ---- CSR build: g-graph (dst over nodes) ----
    hipMemsetAsync(off_g, 0, (size_t)(N + 1) * 4, stream);
    count_kernel<<<(int)((Eg + 255) / 256), 256, 0, stream>>>(eig + Eg, off_g, Eg);
    {
        int nb = (N + 1023) / 1024;
        scan1<<<nb, 256, 0, stream>>>(off_g, part, N);
        scan2<<<1, 1024, 0, stream>>>(part, nb, off_g + N);
        scan3<<<nb, 256, 0, stream>>>(off_g, part, N);
    }
    fill_kernel<<<(int)((Eg + 255) / 256), 256, 0, stream>>>(eig + Eg, off_g, list_g, Eg);
    // ---- CSR build: lg-graph (dst over g-edges) ----
    hipMemsetAsync(off_lg, 0, (size_t)(Eg + 1) * 4, stream);
    count_kernel<<<(int)((Elg + 255) / 256), 256, 0, stream>>>(eilg + Elg, off_lg, Elg);
    {
        int nb = (int)((Eg + 1023) / 1024);
        scan1<<<nb, 256, 0, stream>>>(off_lg, part, (int)Eg);
        scan2<<<1, 1024, 0, stream>>>(part, nb, off_lg + Eg);
        scan3<<<nb, 256, 0, stream>>>(off_lg, part, (int)Eg);
    }
    fill_kernel<<<(int)((Elg + 255) / 256), 256, 0, stream>>>(eilg + Elg, off_lg, list_lg, Elg);

    // jk0 = relu(x @ W_feat^T)
    rowgemm<128, true, false><<<(N + 63) / 64, 256, 0, stream>>>(
        x, W_feat, nullptr, nullptr, jkB, N);
    // initial msgs -> mA (plain stores)
    edge_msg_init<<<(int)((Eg + 127) / 128), 512, 0, stream>>>(
        jkB, eig, eag, W_msg, mA, Eg);
    // jk1 = gather(mA) @ W_lg2g^T + deg*b
    gather_g<<<(N + 3) / 4, 256, 0, stream>>>(mA, list_g, off_g, aggB, deg, N);
    rowgemm<64, false, true><<<(N + 63) / 64, 256, 0, stream>>>(
        aggB, W_lg2g, b_lg2g, deg, jkB + (size_t)N * 64, N);
    // ---- linegraph layer 0: mA -> mB ----
    hipMemsetAsync(mB, 0, (size_t)Eg * 64 * 2, stream);
    edge_msg_lg<<<(int)((Elg + 127) / 128), 512, 0, stream>>>(
        mA, eilg, ealg, W_msg_l, list_lg, mB, Elg);
    gather_g<<<(N + 3) / 4, 256, 0, stream>>>(mB, list_g, off_g, aggB, nullptr, N);
    rowgemm<64, false, true><<<(N + 63) / 64, 256, 0, stream>>>(
        aggB, W_lg2g, b_lg2g, nullptr, jkB + (size_t)2 * N * 64, N);
    // ---- linegraph layer 1: mB -> mA ----
    hipMemsetAsync(mA, 0, (size_t)Eg * 64 * 2, stream);
    edge_msg_lg<<<(int)((Elg + 127) / 128), 512, 0, stream>>>(
        mB, eilg, ealg, W_msg_l + 64 * 144, list_lg, mA, Elg);
    gather_g<<<(N + 3) / 4, 256, 0, stream>>>(mA, list_g, off_g, aggB, nullptr, N);
    rowgemm<64, false, true><<<(N + 63) / 64, 256, 0, stream>>>(
        aggB, W_lg2g, b_lg2g, nullptr, jkB + (size_t)3 * N * 64, N);
    // ---- JK bidirectional LSTM (register-resident weights) ----
    {
        int ntiles = (N + 31) / 32;
        lstm2<<<dim3(512, 2), 512, 0, stream>>>(
            jkB, WhhB, WihB, BS, W_att, scores, N, ntiles);
    }
    final_kernel<<<(N + 3) / 4, 256, 0, stream>>>(
        jkB, scores, W_out, (float*)d_out, N);
}

// Round 6
// 1216.349 us; speedup vs baseline: 2.7236x; 1.1090x over previous
//
#include <hip/hip_runtime.h>

typedef unsigned short u16;
typedef unsigned int u32;
typedef __attribute__((ext_vector_type(8))) short bf16x8;
typedef __attribute__((ext_vector_type(4))) float f32x4;

#define MFMA(a, b, c) __builtin_amdgcn_mfma_f32_16x16x32_bf16(a, b, c, 0, 0, 0)

__device__ __forceinline__ u16 f2bf(float x) {
    union { float f; u32 u; } v; v.f = x;
    u32 r = (v.u + 0x7FFFu + ((v.u >> 16) & 1u)) >> 16;
    return (u16)r;
}
__device__ __forceinline__ float bf2f(u16 b) {
    union { u32 u; float f; } v; v.u = ((u32)b) << 16;
    return v.f;
}
__device__ __forceinline__ void casAddPair(u32* w, float lo, float hi) {
    u32 old = *w, assumed;
    do {
        assumed = old;
        u32 des = (u32)f2bf(bf2f((u16)(assumed & 0xFFFFu)) + lo) |
                  ((u32)f2bf(bf2f((u16)(assumed >> 16)) + hi) << 16);
        if (des == assumed) break;
        old = atomicCAS(w, assumed, des);
    } while (old != assumed);
}

// ---------------------------------------------------------------------------
// prep: convert LSTM weights to bf16, combine biases
__global__ __launch_bounds__(256) void prep_w(
    const float* __restrict__ Whh_f, const float* __restrict__ Whh_b,
    const float* __restrict__ Wih_f, const float* __restrict__ Wih_b,
    const float* __restrict__ bih_f, const float* __restrict__ bhh_f,
    const float* __restrict__ bih_b, const float* __restrict__ bhh_b,
    u16* __restrict__ WhhB, u16* __restrict__ WihB, float* __restrict__ BS)
{
    int i = blockIdx.x * 256 + threadIdx.x;
    if (i < 131072) {
        int d = i >> 16, r = i & 65535;
        WhhB[i] = f2bf(d ? Whh_b[r] : Whh_f[r]);
    } else if (i < 196608) {
        int i2 = i - 131072; int d = i2 >> 15, r = i2 & 32767;
        WihB[i2] = f2bf(d ? Wih_b[r] : Wih_f[r]);
    } else if (i < 197632) {
        int i3 = i - 196608; int d = i3 >> 9, g = i3 & 511;
        BS[i3] = d ? (bih_b[g] + bhh_b[g]) : (bih_f[g] + bhh_f[g]);
    }
}

// ---------------------------------------------------------------------------
// CSR build
__global__ __launch_bounds__(256) void count_kernel(const int* __restrict__ dst,
                                                    u32* __restrict__ cnt, long E)
{
    long i = (long)blockIdx.x * 256 + threadIdx.x;
    if (i < E) atomicAdd(&cnt[dst[i]], 1u);
}

__global__ __launch_bounds__(256) void scan1(const u32* __restrict__ a,
                                             u32* __restrict__ part, int n)
{
    __shared__ u32 ts[256];
    int b = blockIdx.x, t = threadIdx.x;
    long i0 = (long)b * 1024 + t * 4;
    u32 s = 0;
#pragma unroll
    for (int k = 0; k < 4; ++k) { long i = i0 + k; if (i < n) s += a[i]; }
    ts[t] = s; __syncthreads();
    for (int off = 1; off < 256; off <<= 1) {
        u32 x = (t >= off) ? ts[t - off] : 0u;
        __syncthreads(); ts[t] += x; __syncthreads();
    }
    if (t == 255) part[b] = ts[255];
}

__global__ __launch_bounds__(1024) void scan2(u32* __restrict__ part, int nb,
                                              u32* __restrict__ total_out)
{
    __shared__ u32 ts[1024];
    int t = threadIdx.x;
    u32 v = (t < nb) ? part[t] : 0u;
    ts[t] = v; __syncthreads();
    for (int off = 1; off < 1024; off <<= 1) {
        u32 x = (t >= off) ? ts[t - off] : 0u;
        __syncthreads(); ts[t] += x; __syncthreads();
    }
    if (t < nb) part[t] = ts[t] - v;
    if (t == 1023 && total_out) *total_out = ts[1023];
}

__global__ __launch_bounds__(256) void scan3(u32* __restrict__ a,
                                             const u32* __restrict__ part, int n)
{
    __shared__ u32 ts[256];
    int b = blockIdx.x, t = threadIdx.x;
    long i0 = (long)b * 1024 + t * 4;
    u32 v[4]; u32 s = 0;
#pragma unroll
    for (int k = 0; k < 4; ++k) { long i = i0 + k; v[k] = (i < n) ? a[i] : 0u; s += v[k]; }
    ts[t] = s; __syncthreads();
    for (int off = 1; off < 256; off <<= 1) {
        u32 x = (t >= off) ? ts[t - off] : 0u;
        __syncthreads(); ts[t] += x; __syncthreads();
    }
    u32 run = part[b] + ts[t] - s;
#pragma unroll
    for (int k = 0; k < 4; ++k) {
        long i = i0 + k;
        if (i < n) { u32 x = v[k]; a[i] = run; run += x; }
    }
}

__global__ __launch_bounds__(256) void fill_kernel(const int* __restrict__ dst,
                                                   u32* __restrict__ off,
                                                   int* __restrict__ list, long E)
{
    long i = (long)blockIdx.x * 256 + threadIdx.x;
    if (i < E) {
        u32 pos = atomicAdd(&off[dst[i]], 1u);
        list[pos] = (int)i;
    }
}

// ---------------------------------------------------------------------------
// zero_fill: zero only rows needing init (empty buckets + buckets crossing a
// 128-position block boundary, which are CAS-accumulated). offc is the
// fill-corrupted (end-offset) array.
__global__ __launch_bounds__(256) void zero_fill(const u32* __restrict__ offc,
                                                 u16* __restrict__ outb, long NB)
{
    long idx = (long)blockIdx.x * 256 + threadIdx.x;
    long n = idx >> 3; int q = (int)(idx & 7);
    if (n >= NB) return;
    u32 s = n ? offc[n - 1] : 0u;
    u32 e = offc[n];
    bool need = (s == e) || ((s >> 7) != ((e - 1) >> 7));
    if (need) *(uint4*)(outb + n * 64 + q * 8) = make_uint4(0, 0, 0, 0);
}

// ---------------------------------------------------------------------------
// rowgemm: outb[M x 64] (bf16) = act(in[M x K] @ W[64 x K]^T (+ bias*scale))
template <int K, bool RELU, bool INBF16>
__global__ __launch_bounds__(256) void rowgemm(
    const void* __restrict__ in, const float* __restrict__ W,
    const float* __restrict__ bias, const float* __restrict__ bias_scale,
    u16* __restrict__ outb, int M)
{
    constexpr int KP = K + 8;
    __shared__ u16 inS[64 * KP];
    __shared__ u16 WS[64 * KP];
    int t = threadIdx.x;
    long rb = (long)blockIdx.x * 64;
    for (int i = t; i < 64 * K; i += 256) {
        int c = i / K, k = i - c * K;
        WS[c * KP + k] = f2bf(W[i]);
    }
    if (INBF16) {
        const u16* inb = (const u16*)in;
        for (int i = t; i < 64 * K / 8; i += 256) {
            int r = i / (K / 8), q = i - r * (K / 8);
            long gr = rb + r;
            uint4 v = make_uint4(0, 0, 0, 0);
            if (gr < M) v = *(const uint4*)&inb[gr * (long)K + q * 8];
            *(uint4*)&inS[r * KP + q * 8] = v;
        }
    } else {
        const float* inf = (const float*)in;
        for (int i = t; i < 64 * K; i += 256) {
            int r = i / K, k = i - r * K;
            long gr = rb + r;
            inS[r * KP + k] = (gr < M) ? f2bf(inf[gr * (long)K + k]) : (u16)0;
        }
    }
    __syncthreads();
    int l = t & 63, w = t >> 6, lr = l & 15, lq = l >> 4;
    f32x4 acc[4];
#pragma unroll
    for (int i = 0; i < 4; ++i) acc[i] = (f32x4){0.f, 0.f, 0.f, 0.f};
#pragma unroll
    for (int kc = 0; kc < K; kc += 32) {
        bf16x8 a = *(const bf16x8*)&inS[(w * 16 + lr) * KP + kc + lq * 8];
#pragma unroll
        for (int ct = 0; ct < 4; ++ct) {
            bf16x8 b = *(const bf16x8*)&WS[(ct * 16 + lr) * KP + kc + lq * 8];
            acc[ct] = MFMA(a, b, acc[ct]);
        }
    }
#pragma unroll
    for (int ct = 0; ct < 4; ++ct)
#pragma unroll
        for (int r = 0; r < 4; ++r) {
            long gr = rb + w * 16 + lq * 4 + r;
            if (gr < M) {
                int c = ct * 16 + lr;
                float v = acc[ct][r];
                if (bias) v += bias[c] * (bias_scale ? bias_scale[gr] : 1.f);
                if (RELU) v = fmaxf(v, 0.f);
                outb[gr * 64 + c] = f2bf(v);
            }
        }
}

// ---------------------------------------------------------------------------
// edge_msg_init2: direct-gather A-fragments (no inS staging).
// 512 threads, 128 edges/block (16 per wave). Natural order, plain stores.
__global__ __launch_bounds__(512, 4) void edge_msg_init2(
    const u16* __restrict__ feat, const int* __restrict__ ei,
    const float* __restrict__ attr, const float* __restrict__ W,
    u16* __restrict__ outb, long E)
{
    __shared__ u16 WS[64 * 168];    // 21504 B
    __shared__ u16 eds[128 * 64];   // 16384 B
    int t = threadIdx.x;
    long eb = (long)blockIdx.x * 128;
    for (int i = t; i < 64 * 144; i += 512) {
        int c = i / 144, k = i - c * 144;
        WS[c * 168 + k] = f2bf(W[i]);
    }
    for (int i = t; i < 64 * 24; i += 512) {
        int c = i / 24, k = 144 + (i - c * 24);
        WS[c * 168 + k] = 0;
    }
    int w = t >> 6, l = t & 63, lr = l & 15, lq = l >> 4;
    long e = eb + w * 16 + lr;
    long ec = (e < E) ? e : (E - 1);
    int src = ei[ec], dst = ei[E + ec];
    bf16x8 A[5];
    {
        const uint4* sp = (const uint4*)(feat + (long)src * 64);
        const uint4* dp = (const uint4*)(feat + (long)dst * 64);
        *(uint4*)&A[0] = sp[lq];
        *(uint4*)&A[1] = sp[4 + lq];
        *(uint4*)&A[2] = dp[lq];
        *(uint4*)&A[3] = dp[4 + lq];
        uint4 pv = make_uint4(0, 0, 0, 0);
        if (lq < 2) {
            const float4* ap = (const float4*)(attr + ec * 16) + lq * 2;
            float4 b0 = ap[0], b1 = ap[1];
            pv.x = (u32)f2bf(b0.x) | ((u32)f2bf(b0.y) << 16);
            pv.y = (u32)f2bf(b0.z) | ((u32)f2bf(b0.w) << 16);
            pv.z = (u32)f2bf(b1.x) | ((u32)f2bf(b1.y) << 16);
            pv.w = (u32)f2bf(b1.z) | ((u32)f2bf(b1.w) << 16);
        }
        *(uint4*)&A[4] = pv;
    }
    __syncthreads();
    f32x4 acc[4];
#pragma unroll
    for (int ct = 0; ct < 4; ++ct) acc[ct] = (f32x4){0.f, 0.f, 0.f, 0.f};
#pragma unroll
    for (int kc = 0; kc < 5; ++kc) {
#pragma unroll
        for (int ct = 0; ct < 4; ++ct) {
            bf16x8 b = *(const bf16x8*)&WS[(ct * 16 + lr) * 168 + kc * 32 + lq * 8];
            acc[ct] = MFMA(A[kc], b, acc[ct]);
        }
    }
#pragma unroll
    for (int ct = 0; ct < 4; ++ct)
#pragma unroll
        for (int r = 0; r < 4; ++r) {
            int row = w * 16 + lq * 4 + r;
            int col = ct * 16 + lr;
            eds[row * 64 + col] = f2bf(fmaxf(acc[ct][r], 0.f));
        }
    __syncthreads();
    for (int j = t; j < 1024; j += 512) {
        int le = j >> 3, q = j & 7;
        long e2 = eb + le;
        if (e2 < E)
            *(uint4*)(outb + e2 * 64 + q * 8) = *(const uint4*)&eds[le * 64 + q * 8];
    }
}

// ---------------------------------------------------------------------------
// edge_msg_lg2: direct-gather A-frags, dst-sorted (CSR) order, segmented
// reduction epilogue (plain store for intra-block segments, CAS at borders).
__global__ __launch_bounds__(512, 4) void edge_msg_lg2(
    const u16* __restrict__ feat, const int* __restrict__ ei,
    const float* __restrict__ attr, const float* __restrict__ W,
    const int* __restrict__ list, u16* __restrict__ outb, long E)
{
    __shared__ u16 WS[64 * 168];
    __shared__ u16 eds[128 * 64];
    __shared__ int dstS[128];
    __shared__ int idS[128];
    __shared__ int srcS[128];
    __shared__ int dprevS, dnextS;
    int t = threadIdx.x;
    long pb = (long)blockIdx.x * 128;
    for (int i = t; i < 64 * 144; i += 512) {
        int c = i / 144, k = i - c * 144;
        WS[c * 168 + k] = f2bf(W[i]);
    }
    for (int i = t; i < 64 * 24; i += 512) {
        int c = i / 24, k = 144 + (i - c * 24);
        WS[c * 168 + k] = 0;
    }
    if (t < 128) {
        long p = pb + t;
        int id = (p < E) ? list[p] : -1;
        idS[t] = id;
        srcS[t] = (id >= 0) ? ei[id] : 0;
        dstS[t] = (id >= 0) ? ei[E + id] : -1;
    } else if (t == 128) {
        dprevS = (pb > 0) ? ei[E + list[pb - 1]] : -2;
    } else if (t == 129) {
        dnextS = (pb + 128 < E) ? ei[E + list[pb + 128]] : -2;
    }
    __syncthreads();
    int w = t >> 6, l = t & 63, lr = l & 15, lq = l >> 4;
    int el = w * 16 + lr;
    int id = idS[el];
    long idc = (id >= 0) ? (long)id : 0;
    int src = srcS[el];
    int dst = (dstS[el] >= 0) ? dstS[el] : 0;
    bf16x8 A[5];
    {
        const uint4* sp = (const uint4*)(feat + (long)src * 64);
        const uint4* dp = (const uint4*)(feat + (long)dst * 64);
        *(uint4*)&A[0] = sp[lq];
        *(uint4*)&A[1] = sp[4 + lq];
        *(uint4*)&A[2] = dp[lq];
        *(uint4*)&A[3] = dp[4 + lq];
        uint4 pv = make_uint4(0, 0, 0, 0);
        if (lq < 2) {
            const float4* ap = (const float4*)(attr + idc * 16) + lq * 2;
            float4 b0 = ap[0], b1 = ap[1];
            pv.x = (u32)f2bf(b0.x) | ((u32)f2bf(b0.y) << 16);
            pv.y = (u32)f2bf(b0.z) | ((u32)f2bf(b0.w) << 16);
            pv.z = (u32)f2bf(b1.x) | ((u32)f2bf(b1.y) << 16);
            pv.w = (u32)f2bf(b1.z) | ((u32)f2bf(b1.w) << 16);
        }
        *(uint4*)&A[4] = pv;
    }
    f32x4 acc[4];
#pragma unroll
    for (int ct = 0; ct < 4; ++ct) acc[ct] = (f32x4){0.f, 0.f, 0.f, 0.f};
#pragma unroll
    for (int kc = 0; kc < 5; ++kc) {
#pragma unroll
        for (int ct = 0; ct < 4; ++ct) {
            bf16x8 b = *(const bf16x8*)&WS[(ct * 16 + lr) * 168 + kc * 32 + lq * 8];
            acc[ct] = MFMA(A[kc], b, acc[ct]);
        }
    }
#pragma unroll
    for (int ct = 0; ct < 4; ++ct)
#pragma unroll
        for (int r = 0; r < 4; ++r) {
            int row = w * 16 + lq * 4 + r;
            int col = ct * 16 + lr;
            eds[row * 64 + col] = f2bf(fmaxf(acc[ct][r], 0.f));
        }
    __syncthreads();
    for (int j = t; j < 4096; j += 512) {
        int le = j >> 5, wd = j & 31;
        int d = dstS[le];
        if (d < 0) continue;
        if (le > 0 && dstS[le - 1] == d) continue;  // not segment start
        float lo = 0.f, hi = 0.f;
        int le2 = le;
        do {
            u32 pair = *(const u32*)&eds[le2 * 64 + wd * 2];
            lo += bf2f((u16)(pair & 0xFFFFu));
            hi += bf2f((u16)(pair >> 16));
            ++le2;
        } while (le2 < 128 && dstS[le2] == d);
        bool bprev = (le == 0 && dprevS == d);
        bool bnext = (le2 == 128 && dnextS == d);
        u32* dw = (u32*)(outb + (long)d * 64 + wd * 2);
        if (bprev || bnext) {
            casAddPair(dw, lo, hi);
        } else {
            *dw = (u32)f2bf(lo) | ((u32)f2bf(hi) << 16);
        }
    }
}

// ---------------------------------------------------------------------------
// gather_g: aggB[n] = sum over CSR bucket of bf16 msg rows (one wave/node).
__global__ __launch_bounds__(256) void gather_g(
    const u16* __restrict__ m, const int* __restrict__ list,
    const u32* __restrict__ offc, u16* __restrict__ aggB,
    float* __restrict__ degOut, int N)
{
    int t = threadIdx.x, w = t >> 6, l = t & 63;
    long n = (long)blockIdx.x * 4 + w;
    if (n >= N) return;
    u32 start = n ? offc[n - 1] : 0u;
    u32 end = offc[n];
    float s = 0.f;
    for (u32 i = start; i < end; ++i) {
        int e = list[i];
        s += bf2f(m[(long)e * 64 + l]);
    }
    aggB[n * 64 + l] = f2bf(s);
    if (degOut && l == 0) degOut[n] = (float)(end - start);
}

// ---------------------------------------------------------------------------
// lstm2: bidirectional JK-LSTM, weights register-resident (see R4 notes).
__global__ __launch_bounds__(512, 2) void lstm2(
    const u16* __restrict__ jkB, const u16* __restrict__ WhhB,
    const u16* __restrict__ WihB, const float* __restrict__ BS,
    const float* __restrict__ Watt, float* __restrict__ scores,
    int N, int ntiles)
{
    __shared__ u16 hS[32 * 136];
    __shared__ u16 xS[32 * 72];
    __shared__ float WattS[128];
    __shared__ float part[32 * 16];
    int t = threadIdx.x;
    int dir = blockIdx.y;
    int w = t >> 6, l = t & 63, lr = l & 15, lq = l >> 4;
    const u16* WhhD = WhhB + (long)dir * 65536;
    const u16* WihD = WihB + (long)dir * 32768;
    int grow = w * 16 + lr;
    bf16x8 Wh[4][4], Wi[4][2];
    float bs[4];
#pragma unroll
    for (int ty = 0; ty < 4; ++ty) {
        int g = ty * 128 + grow;
#pragma unroll
        for (int kc = 0; kc < 4; ++kc)
            Wh[ty][kc] = *(const bf16x8*)&WhhD[g * 128 + kc * 32 + lq * 8];
#pragma unroll
        for (int kc = 0; kc < 2; ++kc)
            Wi[ty][kc] = *(const bf16x8*)&WihD[g * 64 + kc * 32 + lq * 8];
        bs[ty] = BS[dir * 512 + g];
    }
    if (t < 128) WattS[t] = Watt[dir * 128 + t];
    float* scOut = scores + (long)dir * N * 4;

    for (int tile = blockIdx.x; tile < ntiles; tile += gridDim.x) {
        long n0 = (long)tile * 32;
        __syncthreads();
        for (int i = t; i < 32 * 136; i += 512) hS[i] = 0;
        float creg[2][4] = {};
#pragma unroll 1
        for (int s = 0; s < 4; ++s) {
            int tt = dir ? (3 - s) : s;
            if (t < 256) {
                int n = t >> 3, j = t & 7;
                long gn = n0 + n;
                uint4 v = make_uint4(0, 0, 0, 0);
                if (gn < N) v = *(const uint4*)&jkB[((long)tt * N + gn) * 64 + j * 8];
                *(uint4*)&xS[n * 72 + j * 8] = v;
            }
            __syncthreads();
            f32x4 acc[4][2];
#pragma unroll
            for (int ty = 0; ty < 4; ++ty)
#pragma unroll
                for (int nt = 0; nt < 2; ++nt) {
                    float b0 = bs[ty];
                    acc[ty][nt] = (f32x4){b0, b0, b0, b0};
                }
#pragma unroll
            for (int kc = 0; kc < 4; ++kc) {
                bf16x8 a0 = *(const bf16x8*)&hS[lr * 136 + kc * 32 + lq * 8];
                bf16x8 a1 = *(const bf16x8*)&hS[(16 + lr) * 136 + kc * 32 + lq * 8];
#pragma unroll
                for (int ty = 0; ty < 4; ++ty) {
                    acc[ty][0] = MFMA(a0, Wh[ty][kc], acc[ty][0]);
                    acc[ty][1] = MFMA(a1, Wh[ty][kc], acc[ty][1]);
                }
            }
#pragma unroll
            for (int kc = 0; kc < 2; ++kc) {
                bf16x8 a0 = *(const bf16x8*)&xS[lr * 72 + kc * 32 + lq * 8];
                bf16x8 a1 = *(const bf16x8*)&xS[(16 + lr) * 72 + kc * 32 + lq * 8];
#pragma unroll
                for (int ty = 0; ty < 4; ++ty) {
                    acc[ty][0] = MFMA(a0, Wi[ty][kc], acc[ty][0]);
                    acc[ty][1] = MFMA(a1, Wi[ty][kc], acc[ty][1]);
                }
            }
            __syncthreads();
#pragma unroll
            for (int nt = 0; nt < 2; ++nt)
#pragma unroll
                for (int r = 0; r < 4; ++r) {
                    float iv = acc[0][nt][r], fv = acc[1][nt][r];
                    float gv = acc[2][nt][r], ov = acc[3][nt][r];
                    float c = creg[nt][r];
                    float si = 1.f / (1.f + __expf(-iv));
                    float sf = 1.f / (1.f + __expf(-fv));
                    float tg = 2.f / (1.f + __expf(-2.f * gv)) - 1.f;
                    c = sf * c + si * tg;
                    float so = 1.f / (1.f + __expf(-ov));
                    float th = 2.f / (1.f + __expf(-2.f * c)) - 1.f;
                    creg[nt][r] = c;
                    int node = nt * 16 + lq * 4 + r;
                    hS[node * 136 + grow] = f2bf(so * th);
                }
            __syncthreads();
            {
                int n = t & 31, ck = t >> 5;
                float sum = 0.f;
#pragma unroll
                for (int j = 0; j < 8; ++j)
                    sum += bf2f(hS[n * 136 + ck * 8 + j]) * WattS[ck * 8 + j];
                part[n * 16 + ck] = sum;
            }
            __syncthreads();
            if (t < 32) {
                long gn = n0 + t;
                if (gn < N) {
                    float v = 0.f;
#pragma unroll
                    for (int j = 0; j < 16; ++j) v += part[t * 16 + j];
                    scOut[gn * 4 + tt] = v;
                }
            }
        }
    }
}

// ---------------------------------------------------------------------------
__global__ __launch_bounds__(256) void final_kernel(
    const u16* __restrict__ jkB, const float* __restrict__ scores,
    const float* __restrict__ Wout, float* __restrict__ out, int N)
{
    __shared__ float feS[4][64];
    int t = threadIdx.x, l = t & 63, w = t >> 6;
    long n = (long)blockIdx.x * 4 + w;
    bool ok = (n < N);
    long nn = ok ? n : (long)(N - 1);
    float sc[4];
#pragma unroll
    for (int tt = 0; tt < 4; ++tt)
        sc[tt] = scores[nn * 4 + tt] + scores[(long)N * 4 + nn * 4 + tt];
    float m = fmaxf(fmaxf(sc[0], sc[1]), fmaxf(sc[2], sc[3]));
    float e0 = __expf(sc[0] - m), e1 = __expf(sc[1] - m);
    float e2 = __expf(sc[2] - m), e3 = __expf(sc[3] - m);
    float den = e0 + e1 + e2 + e3;
    float a0 = e0 / den, a1 = e1 / den, a2 = e2 / den, a3 = e3 / den;
    float fe = a0 * bf2f(jkB[nn * 64 + l]) + a1 * bf2f(jkB[((long)N + nn) * 64 + l]) +
               a2 * bf2f(jkB[((long)2 * N + nn) * 64 + l]) +
               a3 * bf2f(jkB[((long)3 * N + nn) * 64 + l]);
    feS[w][l] = fe;
    __syncthreads();
    float logit = 0.f;
    if (l < 40)
        for (int c = 0; c < 64; ++c) logit += feS[w][c] * Wout[l * 64 + c];
    float v = (l < 40) ? logit : -1e30f;
    for (int off = 32; off; off >>= 1) v = fmaxf(v, __shfl_xor(v, off));
    float ex = (l < 40) ? __expf(logit - v) : 0.f;
    for (int off = 32; off; off >>= 1) ex += __shfl_xor(ex, off);
    if (ok && l < 40) out[n * 40 + l] = logit - v - __logf(ex);
}

// ---------------------------------------------------------------------------
extern "C" void kernel_launch(void* const* d_in, const int* in_sizes, int n_in,
                              void* d_out, int out_size, void* d_ws, size_t ws_size,
                              hipStream_t stream)
{
    const float* x        = (const float*)d_in[0];
    const int*   eig      = (const int*)d_in[1];
    const float* eag      = (const float*)d_in[2];
    const int*   eilg     = (const int*)d_in[3];
    const float* ealg     = (const float*)d_in[4];
    const float* W_feat   = (const float*)d_in[5];
    const float* W_msg    = (const float*)d_in[6];
    const float* W_lg2g   = (const float*)d_in[7];
    const float* b_lg2g   = (const float*)d_in[8];
    const float* W_msg_l  = (const float*)d_in[9];
    const float* Wih_f    = (const float*)d_in[10];
    const float* Whh_f    = (const float*)d_in[11];
    const float* bih_f    = (const float*)d_in[12];
    const float* bhh_f    = (const float*)d_in[13];
    const float* Wih_b    = (const float*)d_in[14];
    const float* Whh_b    = (const float*)d_in[15];
    const float* bih_b    = (const float*)d_in[16];
    const float* bhh_b    = (const float*)d_in[17];
    const float* W_att    = (const float*)d_in[18];
    const float* W_out    = (const float*)d_in[20];

    int  N   = in_sizes[0] / 128;
    long Eg  = in_sizes[1] / 2;
    long Elg = in_sizes[3] / 2;

    char* wp = (char*)d_ws;
    auto alloc = [&](size_t bytes) -> char* {
        char* p = wp; wp += (bytes + 255) & ~(size_t)255; return p;
    };
    u16*   jkB    = (u16*)  alloc((size_t)4 * N * 64 * 2);
    u16*   mA     = (u16*)  alloc((size_t)Eg * 64 * 2);
    u16*   mB     = (u16*)  alloc((size_t)Eg * 64 * 2);
    u16*   aggB   = (u16*)  alloc((size_t)N * 64 * 2);
    float* deg    = (float*)alloc((size_t)N * 4);
    float* scores = (float*)alloc((size_t)2 * N * 4 * 4);
    u16*   WhhB   = (u16*)  alloc((size_t)2 * 65536 * 2);
    u16*   WihB   = (u16*)  alloc((size_t)2 * 32768 * 2);
    float* BS     = (float*)alloc((size_t)2 * 512 * 4);
    u32*   off_g  = (u32*)  alloc((size_t)(N + 1) * 4);
    int*   list_g = (int*)  alloc((size_t)Eg * 4);
    u32*   off_lg = (u32*)  alloc((size_t)(Eg + 1) * 4);
    int*   list_lg= (int*)  alloc((size_t)Elg * 4);
    u32*   part   = (u32*)  alloc((size_t)1024 * 4);

    prep_w<<<772, 256, 0, stream>>>(Whh_f, Whh_b, Wih_f, Wih_b,
                                    bih_f, bhh_f, bih_b, bhh_b, WhhB, WihB, BS);
    // ---- CSR build: g-graph (dst over nodes) ----
    hipMemsetAsync(off_g, 0, (size_t)(N + 1) * 4, stream);
    count_kernel<<<(int)((Eg + 255) / 256), 256, 0, stream>>>(eig + Eg, off_g, Eg);
    {
        int nb = (N + 1023) / 1024;
        scan1<<<nb, 256, 0, stream>>>(off_g, part, N);
        scan2<<<1, 1024, 0, stream>>>(part, nb, off_g + N);
        scan3<<<nb, 256, 0, stream>>>(off_g, part, N);
    }
    fill_kernel<<<(int)((Eg + 255) / 256), 256, 0, stream>>>(eig + Eg, off_g, list_g, Eg);
    // ---- CSR build: lg-graph (dst over g-edges) ----
    hipMemsetAsync(off_lg, 0, (size_t)(Eg + 1) * 4, stream);
    count_kernel<<<(int)((Elg + 255) / 256), 256, 0, stream>>>(eilg + Elg, off_lg, Elg);
    {
        int nb = (int)((Eg + 1023) / 1024);
        scan1<<<nb, 256, 0, stream>>>(off_lg, part, (int)Eg);
        scan2<<<1, 1024, 0, stream>>>(part, nb, off_lg + Eg);
        scan3<<<nb, 256, 0, stream>>>(off_lg, part, (int)Eg);
    }
    fill_kernel<<<(int)((Elg + 255) / 256), 256, 0, stream>>>(eilg + Elg, off_lg, list_lg, Elg);

    // jk0 = relu(x @ W_feat^T)
    rowgemm<128, true, false><<<(N + 63) / 64, 256, 0, stream>>>(
        x, W_feat, nullptr, nullptr, jkB, N);
    // initial msgs -> mA (plain stores)
    edge_msg_init2<<<(int)((Eg + 127) / 128), 512, 0, stream>>>(
        jkB, eig, eag, W_msg, mA, Eg);
    // jk1 = gather(mA) @ W_lg2g^T + deg*b
    gather_g<<<(N + 3) / 4, 256, 0, stream>>>(mA, list_g, off_g, aggB, deg, N);
    rowgemm<64, false, true><<<(N + 63) / 64, 256, 0, stream>>>(
        aggB, W_lg2g, b_lg2g, deg, jkB + (size_t)N * 64, N);
    // ---- linegraph layer 0: mA -> mB ----
    zero_fill<<<(int)((Eg * 8 + 255) / 256), 256, 0, stream>>>(off_lg, mB, Eg);
    edge_msg_lg2<<<(int)((Elg + 127) / 128), 512, 0, stream>>>(
        mA, eilg, ealg, W_msg_l, list_lg, mB, Elg);
    gather_g<<<(N + 3) / 4, 256, 0, stream>>>(mB, list_g, off_g, aggB, nullptr, N);
    rowgemm<64, false, true><<<(N + 63) / 64, 256, 0, stream>>>(
        aggB, W_lg2g, b_lg2g, nullptr, jkB + (size_t)2 * N * 64, N);
    // ---- linegraph layer 1: mB -> mA ----
    zero_fill<<<(int)((Eg * 8 + 255) / 256), 256, 0, stream>>>(off_lg, mA, Eg);
    edge_msg_lg2<<<(int)((Elg + 127) / 128), 512, 0, stream>>>(
        mB, eilg, ealg, W_msg_l + 64 * 144, list_lg, mA, Elg);
    gather_g<<<(N + 3) / 4, 256, 0, stream>>>(mA, list_g, off_g, aggB, nullptr, N);
    rowgemm<64, false, true><<<(N + 63) / 64, 256, 0, stream>>>(
        aggB, W_lg2g, b_lg2g, nullptr, jkB + (size_t)3 * N * 64, N);
    // ---- JK bidirectional LSTM (register-resident weights) ----
    {
        int ntiles = (N + 31) / 32;
        lstm2<<<dim3(512, 2), 512, 0, stream>>>(
            jkB, WhhB, WihB, BS, W_att, scores, N, ntiles);
    }
    final_kernel<<<(N + 3) / 4, 256, 0, stream>>>(
        jkB, scores, W_out, (float*)d_out, N);
}

// Round 7
// 1137.272 us; speedup vs baseline: 2.9130x; 1.0695x over previous
//
#include <hip/hip_runtime.h>

typedef unsigned short u16;
typedef unsigned int u32;
typedef __attribute__((ext_vector_type(8))) short bf16x8;
typedef __attribute__((ext_vector_type(4))) float f32x4;

#define MFMA(a, b, c) __builtin_amdgcn_mfma_f32_16x16x32_bf16(a, b, c, 0, 0, 0)

__device__ __forceinline__ u16 f2bf(float x) {
    union { float f; u32 u; } v; v.f = x;
    u32 r = (v.u + 0x7FFFu + ((v.u >> 16) & 1u)) >> 16;
    return (u16)r;
}
__device__ __forceinline__ float bf2f(u16 b) {
    union { u32 u; float f; } v; v.u = ((u32)b) << 16;
    return v.f;
}
__device__ __forceinline__ void casAddPair(u32* w, float lo, float hi) {
    u32 old = *w, assumed;
    do {
        assumed = old;
        u32 des = (u32)f2bf(bf2f((u16)(assumed & 0xFFFFu)) + lo) |
                  ((u32)f2bf(bf2f((u16)(assumed >> 16)) + hi) << 16);
        if (des == assumed) break;
        old = atomicCAS(w, assumed, des);
    } while (old != assumed);
}

// ---------------------------------------------------------------------------
// prep: convert LSTM weights to bf16, combine biases
__global__ __launch_bounds__(256) void prep_w(
    const float* __restrict__ Whh_f, const float* __restrict__ Whh_b,
    const float* __restrict__ Wih_f, const float* __restrict__ Wih_b,
    const float* __restrict__ bih_f, const float* __restrict__ bhh_f,
    const float* __restrict__ bih_b, const float* __restrict__ bhh_b,
    u16* __restrict__ WhhB, u16* __restrict__ WihB, float* __restrict__ BS)
{
    int i = blockIdx.x * 256 + threadIdx.x;
    if (i < 131072) {
        int d = i >> 16, r = i & 65535;
        WhhB[i] = f2bf(d ? Whh_b[r] : Whh_f[r]);
    } else if (i < 196608) {
        int i2 = i - 131072; int d = i2 >> 15, r = i2 & 32767;
        WihB[i2] = f2bf(d ? Wih_b[r] : Wih_f[r]);
    } else if (i < 197632) {
        int i3 = i - 196608; int d = i3 >> 9, g = i3 & 511;
        BS[i3] = d ? (bih_b[g] + bhh_b[g]) : (bih_f[g] + bhh_f[g]);
    }
}

// ---------------------------------------------------------------------------
// CSR build
__global__ __launch_bounds__(256) void count_kernel(const int* __restrict__ dst,
                                                    u32* __restrict__ cnt, long E)
{
    long i = (long)blockIdx.x * 256 + threadIdx.x;
    if (i < E) atomicAdd(&cnt[dst[i]], 1u);
}

__global__ __launch_bounds__(256) void scan1(const u32* __restrict__ a,
                                             u32* __restrict__ part, int n)
{
    __shared__ u32 ts[256];
    int b = blockIdx.x, t = threadIdx.x;
    long i0 = (long)b * 1024 + t * 4;
    u32 s = 0;
#pragma unroll
    for (int k = 0; k < 4; ++k) { long i = i0 + k; if (i < n) s += a[i]; }
    ts[t] = s; __syncthreads();
    for (int off = 1; off < 256; off <<= 1) {
        u32 x = (t >= off) ? ts[t - off] : 0u;
        __syncthreads(); ts[t] += x; __syncthreads();
    }
    if (t == 255) part[b] = ts[255];
}

__global__ __launch_bounds__(1024) void scan2(u32* __restrict__ part, int nb,
                                              u32* __restrict__ total_out)
{
    __shared__ u32 ts[1024];
    int t = threadIdx.x;
    u32 v = (t < nb) ? part[t] : 0u;
    ts[t] = v; __syncthreads();
    for (int off = 1; off < 1024; off <<= 1) {
        u32 x = (t >= off) ? ts[t - off] : 0u;
        __syncthreads(); ts[t] += x; __syncthreads();
    }
    if (t < nb) part[t] = ts[t] - v;
    if (t == 1023 && total_out) *total_out = ts[1023];
}

__global__ __launch_bounds__(256) void scan3(u32* __restrict__ a,
                                             const u32* __restrict__ part, int n)
{
    __shared__ u32 ts[256];
    int b = blockIdx.x, t = threadIdx.x;
    long i0 = (long)b * 1024 + t * 4;
    u32 v[4]; u32 s = 0;
#pragma unroll
    for (int k = 0; k < 4; ++k) { long i = i0 + k; v[k] = (i < n) ? a[i] : 0u; s += v[k]; }
    ts[t] = s; __syncthreads();
    for (int off = 1; off < 256; off <<= 1) {
        u32 x = (t >= off) ? ts[t - off] : 0u;
        __syncthreads(); ts[t] += x; __syncthreads();
    }
    u32 run = part[b] + ts[t] - s;
#pragma unroll
    for (int k = 0; k < 4; ++k) {
        long i = i0 + k;
        if (i < n) { u32 x = v[k]; a[i] = run; run += x; }
    }
}

__global__ __launch_bounds__(256) void fill_kernel(const int* __restrict__ dst,
                                                   u32* __restrict__ off,
                                                   int* __restrict__ list, long E)
{
    long i = (long)blockIdx.x * 256 + threadIdx.x;
    if (i < E) {
        u32 pos = atomicAdd(&off[dst[i]], 1u);
        list[pos] = (int)i;
    }
}

// ---------------------------------------------------------------------------
// zero_fill: zero only rows needing init (empty buckets + buckets crossing a
// 128-position block boundary, which are CAS-accumulated).
__global__ __launch_bounds__(256) void zero_fill(const u32* __restrict__ offc,
                                                 u16* __restrict__ outb, long NB)
{
    long idx = (long)blockIdx.x * 256 + threadIdx.x;
    long n = idx >> 3; int q = (int)(idx & 7);
    if (n >= NB) return;
    u32 s = n ? offc[n - 1] : 0u;
    u32 e = offc[n];
    bool need = (s == e) || ((s >> 7) != ((e - 1) >> 7));
    if (need) *(uint4*)(outb + n * 64 + q * 8) = make_uint4(0, 0, 0, 0);
}

// ---------------------------------------------------------------------------
// rowgemm: outb[M x 64] (bf16) = act(in[M x K] @ W[64 x K]^T (+ bias*scale))
template <int K, bool RELU, bool INBF16>
__global__ __launch_bounds__(256) void rowgemm(
    const void* __restrict__ in, const float* __restrict__ W,
    const float* __restrict__ bias, const float* __restrict__ bias_scale,
    u16* __restrict__ outb, int M)
{
    constexpr int KP = K + 8;
    __shared__ u16 inS[64 * KP];
    __shared__ u16 WS[64 * KP];
    int t = threadIdx.x;
    long rb = (long)blockIdx.x * 64;
    for (int i = t; i < 64 * K; i += 256) {
        int c = i / K, k = i - c * K;
        WS[c * KP + k] = f2bf(W[i]);
    }
    if (INBF16) {
        const u16* inb = (const u16*)in;
        for (int i = t; i < 64 * K / 8; i += 256) {
            int r = i / (K / 8), q = i - r * (K / 8);
            long gr = rb + r;
            uint4 v = make_uint4(0, 0, 0, 0);
            if (gr < M) v = *(const uint4*)&inb[gr * (long)K + q * 8];
            *(uint4*)&inS[r * KP + q * 8] = v;
        }
    } else {
        const float* inf = (const float*)in;
        for (int i = t; i < 64 * K; i += 256) {
            int r = i / K, k = i - r * K;
            long gr = rb + r;
            inS[r * KP + k] = (gr < M) ? f2bf(inf[gr * (long)K + k]) : (u16)0;
        }
    }
    __syncthreads();
    int l = t & 63, w = t >> 6, lr = l & 15, lq = l >> 4;
    f32x4 acc[4];
#pragma unroll
    for (int i = 0; i < 4; ++i) acc[i] = (f32x4){0.f, 0.f, 0.f, 0.f};
#pragma unroll
    for (int kc = 0; kc < K; kc += 32) {
        bf16x8 a = *(const bf16x8*)&inS[(w * 16 + lr) * KP + kc + lq * 8];
#pragma unroll
        for (int ct = 0; ct < 4; ++ct) {
            bf16x8 b = *(const bf16x8*)&WS[(ct * 16 + lr) * KP + kc + lq * 8];
            acc[ct] = MFMA(a, b, acc[ct]);
        }
    }
#pragma unroll
    for (int ct = 0; ct < 4; ++ct)
#pragma unroll
        for (int r = 0; r < 4; ++r) {
            long gr = rb + w * 16 + lq * 4 + r;
            if (gr < M) {
                int c = ct * 16 + lr;
                float v = acc[ct][r];
                if (bias) v += bias[c] * (bias_scale ? bias_scale[gr] : 1.f);
                if (RELU) v = fmaxf(v, 0.f);
                outb[gr * 64 + c] = f2bf(v);
            }
        }
}

// ---------------------------------------------------------------------------
// edge_msg_init2: direct-gather A-fragments (no inS staging).
__global__ __launch_bounds__(512, 4) void edge_msg_init2(
    const u16* __restrict__ feat, const int* __restrict__ ei,
    const float* __restrict__ attr, const float* __restrict__ W,
    u16* __restrict__ outb, long E)
{
    __shared__ u16 WS[64 * 168];
    __shared__ u16 eds[128 * 64];
    int t = threadIdx.x;
    long eb = (long)blockIdx.x * 128;
    for (int i = t; i < 64 * 144; i += 512) {
        int c = i / 144, k = i - c * 144;
        WS[c * 168 + k] = f2bf(W[i]);
    }
    for (int i = t; i < 64 * 24; i += 512) {
        int c = i / 24, k = 144 + (i - c * 24);
        WS[c * 168 + k] = 0;
    }
    int w = t >> 6, l = t & 63, lr = l & 15, lq = l >> 4;
    long e = eb + w * 16 + lr;
    long ec = (e < E) ? e : (E - 1);
    int src = ei[ec], dst = ei[E + ec];
    bf16x8 A[5];
    {
        const uint4* sp = (const uint4*)(feat + (long)src * 64);
        const uint4* dp = (const uint4*)(feat + (long)dst * 64);
        *(uint4*)&A[0] = sp[lq];
        *(uint4*)&A[1] = sp[4 + lq];
        *(uint4*)&A[2] = dp[lq];
        *(uint4*)&A[3] = dp[4 + lq];
        uint4 pv = make_uint4(0, 0, 0, 0);
        if (lq < 2) {
            const float4* ap = (const float4*)(attr + ec * 16) + lq * 2;
            float4 b0 = ap[0], b1 = ap[1];
            pv.x = (u32)f2bf(b0.x) | ((u32)f2bf(b0.y) << 16);
            pv.y = (u32)f2bf(b0.z) | ((u32)f2bf(b0.w) << 16);
            pv.z = (u32)f2bf(b1.x) | ((u32)f2bf(b1.y) << 16);
            pv.w = (u32)f2bf(b1.z) | ((u32)f2bf(b1.w) << 16);
        }
        *(uint4*)&A[4] = pv;
    }
    __syncthreads();
    f32x4 acc[4];
#pragma unroll
    for (int ct = 0; ct < 4; ++ct) acc[ct] = (f32x4){0.f, 0.f, 0.f, 0.f};
#pragma unroll
    for (int kc = 0; kc < 5; ++kc) {
#pragma unroll
        for (int ct = 0; ct < 4; ++ct) {
            bf16x8 b = *(const bf16x8*)&WS[(ct * 16 + lr) * 168 + kc * 32 + lq * 8];
            acc[ct] = MFMA(A[kc], b, acc[ct]);
        }
    }
#pragma unroll
    for (int ct = 0; ct < 4; ++ct)
#pragma unroll
        for (int r = 0; r < 4; ++r) {
            int row = w * 16 + lq * 4 + r;
            int col = ct * 16 + lr;
            eds[row * 64 + col] = f2bf(fmaxf(acc[ct][r], 0.f));
        }
    __syncthreads();
    for (int j = t; j < 1024; j += 512) {
        int le = j >> 3, q = j & 7;
        long e2 = eb + le;
        if (e2 < E)
            *(uint4*)(outb + e2 * 64 + q * 8) = *(const uint4*)&eds[le * 64 + q * 8];
    }
}

// ---------------------------------------------------------------------------
// edge_msg_lg2: direct-gather A-frags, dst-sorted (CSR) order, segmented
// reduction epilogue (plain store for intra-block segments, CAS at borders).
__global__ __launch_bounds__(512, 4) void edge_msg_lg2(
    const u16* __restrict__ feat, const int* __restrict__ ei,
    const float* __restrict__ attr, const float* __restrict__ W,
    const int* __restrict__ list, u16* __restrict__ outb, long E)
{
    __shared__ u16 WS[64 * 168];
    __shared__ u16 eds[128 * 64];
    __shared__ int dstS[128];
    __shared__ int idS[128];
    __shared__ int srcS[128];
    __shared__ int dprevS, dnextS;
    int t = threadIdx.x;
    long pb = (long)blockIdx.x * 128;
    for (int i = t; i < 64 * 144; i += 512) {
        int c = i / 144, k = i - c * 144;
        WS[c * 168 + k] = f2bf(W[i]);
    }
    for (int i = t; i < 64 * 24; i += 512) {
        int c = i / 24, k = 144 + (i - c * 24);
        WS[c * 168 + k] = 0;
    }
    if (t < 128) {
        long p = pb + t;
        int id = (p < E) ? list[p] : -1;
        idS[t] = id;
        srcS[t] = (id >= 0) ? ei[id] : 0;
        dstS[t] = (id >= 0) ? ei[E + id] : -1;
    } else if (t == 128) {
        dprevS = (pb > 0) ? ei[E + list[pb - 1]] : -2;
    } else if (t == 129) {
        dnextS = (pb + 128 < E) ? ei[E + list[pb + 128]] : -2;
    }
    __syncthreads();
    int w = t >> 6, l = t & 63, lr = l & 15, lq = l >> 4;
    int el = w * 16 + lr;
    int id = idS[el];
    long idc = (id >= 0) ? (long)id : 0;
    int src = srcS[el];
    int dst = (dstS[el] >= 0) ? dstS[el] : 0;
    bf16x8 A[5];
    {
        const uint4* sp = (const uint4*)(feat + (long)src * 64);
        const uint4* dp = (const uint4*)(feat + (long)dst * 64);
        *(uint4*)&A[0] = sp[lq];
        *(uint4*)&A[1] = sp[4 + lq];
        *(uint4*)&A[2] = dp[lq];
        *(uint4*)&A[3] = dp[4 + lq];
        uint4 pv = make_uint4(0, 0, 0, 0);
        if (lq < 2) {
            const float4* ap = (const float4*)(attr + idc * 16) + lq * 2;
            float4 b0 = ap[0], b1 = ap[1];
            pv.x = (u32)f2bf(b0.x) | ((u32)f2bf(b0.y) << 16);
            pv.y = (u32)f2bf(b0.z) | ((u32)f2bf(b0.w) << 16);
            pv.z = (u32)f2bf(b1.x) | ((u32)f2bf(b1.y) << 16);
            pv.w = (u32)f2bf(b1.z) | ((u32)f2bf(b1.w) << 16);
        }
        *(uint4*)&A[4] = pv;
    }
    f32x4 acc[4];
#pragma unroll
    for (int ct = 0; ct < 4; ++ct) acc[ct] = (f32x4){0.f, 0.f, 0.f, 0.f};
#pragma unroll
    for (int kc = 0; kc < 5; ++kc) {
#pragma unroll
        for (int ct = 0; ct < 4; ++ct) {
            bf16x8 b = *(const bf16x8*)&WS[(ct * 16 + lr) * 168 + kc * 32 + lq * 8];
            acc[ct] = MFMA(A[kc], b, acc[ct]);
        }
    }
#pragma unroll
    for (int ct = 0; ct < 4; ++ct)
#pragma unroll
        for (int r = 0; r < 4; ++r) {
            int row = w * 16 + lq * 4 + r;
            int col = ct * 16 + lr;
            eds[row * 64 + col] = f2bf(fmaxf(acc[ct][r], 0.f));
        }
    __syncthreads();
    for (int j = t; j < 4096; j += 512) {
        int le = j >> 5, wd = j & 31;
        int d = dstS[le];
        if (d < 0) continue;
        if (le > 0 && dstS[le - 1] == d) continue;  // not segment start
        float lo = 0.f, hi = 0.f;
        int le2 = le;
        do {
            u32 pair = *(const u32*)&eds[le2 * 64 + wd * 2];
            lo += bf2f((u16)(pair & 0xFFFFu));
            hi += bf2f((u16)(pair >> 16));
            ++le2;
        } while (le2 < 128 && dstS[le2] == d);
        bool bprev = (le == 0 && dprevS == d);
        bool bnext = (le2 == 128 && dnextS == d);
        u32* dw = (u32*)(outb + (long)d * 64 + wd * 2);
        if (bprev || bnext) {
            casAddPair(dw, lo, hi);
        } else {
            *dw = (u32)f2bf(lo) | ((u32)f2bf(hi) << 16);
        }
    }
}

// ---------------------------------------------------------------------------
// gather_g: half-wave (32 lanes, u32 channel pairs) per node; 8 nodes/block.
__global__ __launch_bounds__(256) void gather_g(
    const u16* __restrict__ m, const int* __restrict__ list,
    const u32* __restrict__ offc, u16* __restrict__ aggB,
    float* __restrict__ degOut, int N)
{
    int t = threadIdx.x;
    int hw = t >> 5, c = t & 31;
    long n = (long)blockIdx.x * 8 + hw;
    if (n >= N) return;
    u32 start = n ? offc[n - 1] : 0u;
    u32 end = offc[n];
    float s0 = 0.f, s1 = 0.f;
    for (u32 i = start; i < end; ++i) {
        int e = list[i];
        u32 pair = *(const u32*)&m[(long)e * 64 + c * 2];
        s0 += bf2f((u16)(pair & 0xFFFFu));
        s1 += bf2f((u16)(pair >> 16));
    }
    *(u32*)&aggB[n * 64 + c * 2] = (u32)f2bf(s0) | ((u32)f2bf(s1) << 16);
    if (degOut && c == 0) degOut[n] = (float)(end - start);
}

// ---------------------------------------------------------------------------
// lstm3: bidirectional JK-LSTM, weights register-resident, 64 nodes/tile.
// 512 threads = 8 waves; wave w owns hidden units [16w,16w+16) for all 4 gate
// types; acc covers 4 node-quarters (64 nodes). dir = blockIdx.y.
__global__ __launch_bounds__(512, 2) void lstm3(
    const u16* __restrict__ jkB, const u16* __restrict__ WhhB,
    const u16* __restrict__ WihB, const float* __restrict__ BS,
    const float* __restrict__ Watt, float* __restrict__ scores,
    int N, int ntiles)
{
    __shared__ u16 hS[64 * 136];     // 17408 B
    __shared__ u16 xS[64 * 72];      // 9216 B
    __shared__ float WattS[128];
    __shared__ float part[64 * 8];
    int t = threadIdx.x;
    int dir = blockIdx.y;
    int w = t >> 6, l = t & 63, lr = l & 15, lq = l >> 4;
    const u16* WhhD = WhhB + (long)dir * 65536;
    const u16* WihD = WihB + (long)dir * 32768;
    int grow = w * 16 + lr;
    bf16x8 Wh[4][4], Wi[4][2];
    float bs[4];
#pragma unroll
    for (int ty = 0; ty < 4; ++ty) {
        int g = ty * 128 + grow;
#pragma unroll
        for (int kc = 0; kc < 4; ++kc)
            Wh[ty][kc] = *(const bf16x8*)&WhhD[g * 128 + kc * 32 + lq * 8];
#pragma unroll
        for (int kc = 0; kc < 2; ++kc)
            Wi[ty][kc] = *(const bf16x8*)&WihD[g * 64 + kc * 32 + lq * 8];
        bs[ty] = BS[dir * 512 + g];
    }
    if (t < 128) WattS[t] = Watt[dir * 128 + t];
    float* scOut = scores + (long)dir * N * 4;

    for (int tile = blockIdx.x; tile < ntiles; tile += gridDim.x) {
        long n0 = (long)tile * 64;
        __syncthreads();                        // prev tile's hS reads done
        for (int i = t; i < 64 * 136; i += 512) hS[i] = 0;
        float creg[4][4] = {};
#pragma unroll 1
        for (int s = 0; s < 4; ++s) {
            int tt = dir ? (3 - s) : s;
            {                                   // stage x_t: 64 nodes x 8 uint4
                int n = t >> 3, j = t & 7;
                long gn = n0 + n;
                uint4 v = make_uint4(0, 0, 0, 0);
                if (gn < N) v = *(const uint4*)&jkB[((long)tt * N + gn) * 64 + j * 8];
                *(uint4*)&xS[n * 72 + j * 8] = v;
            }
            __syncthreads();                    // hS zero/write + xS visible
            f32x4 acc[4][4];
#pragma unroll
            for (int ty = 0; ty < 4; ++ty)
#pragma unroll
                for (int nt = 0; nt < 4; ++nt) {
                    float b0 = bs[ty];
                    acc[ty][nt] = (f32x4){b0, b0, b0, b0};
                }
#pragma unroll
            for (int kc = 0; kc < 4; ++kc) {
                bf16x8 a[4];
#pragma unroll
                for (int nt = 0; nt < 4; ++nt)
                    a[nt] = *(const bf16x8*)&hS[(nt * 16 + lr) * 136 + kc * 32 + lq * 8];
#pragma unroll
                for (int ty = 0; ty < 4; ++ty)
#pragma unroll
                    for (int nt = 0; nt < 4; ++nt)
                        acc[ty][nt] = MFMA(a[nt], Wh[ty][kc], acc[ty][nt]);
            }
#pragma unroll
            for (int kc = 0; kc < 2; ++kc) {
                bf16x8 a[4];
#pragma unroll
                for (int nt = 0; nt < 4; ++nt)
                    a[nt] = *(const bf16x8*)&xS[(nt * 16 + lr) * 72 + kc * 32 + lq * 8];
#pragma unroll
                for (int ty = 0; ty < 4; ++ty)
#pragma unroll
                    for (int nt = 0; nt < 4; ++nt)
                        acc[ty][nt] = MFMA(a[nt], Wi[ty][kc], acc[ty][nt]);
            }
            __syncthreads();                    // all hS reads done
#pragma unroll
            for (int nt = 0; nt < 4; ++nt)
#pragma unroll
                for (int r = 0; r < 4; ++r) {
                    float iv = acc[0][nt][r], fv = acc[1][nt][r];
                    float gv = acc[2][nt][r], ov = acc[3][nt][r];
                    float c = creg[nt][r];
                    float si = 1.f / (1.f + __expf(-iv));
                    float sf = 1.f / (1.f + __expf(-fv));
                    float tg = 2.f / (1.f + __expf(-2.f * gv)) - 1.f;
                    c = sf * c + si * tg;
                    float so = 1.f / (1.f + __expf(-ov));
                    float th = 2.f / (1.f + __expf(-2.f * c)) - 1.f;
                    creg[nt][r] = c;
                    int node = nt * 16 + lq * 4 + r;
                    hS[node * 136 + grow] = f2bf(so * th);
                }
            __syncthreads();                    // new h visible
            {
                int n = t & 63, ck = t >> 6;    // ck in [0,8)
                float sum = 0.f;
#pragma unroll
                for (int j = 0; j < 16; ++j)
                    sum += bf2f(hS[n * 136 + ck * 16 + j]) * WattS[ck * 16 + j];
                part[n * 8 + ck] = sum;
            }
            __syncthreads();
            if (t < 64) {
                long gn = n0 + t;
                if (gn < N) {
                    float v = 0.f;
#pragma unroll
                    for (int j = 0; j < 8; ++j) v += part[t * 8 + j];
                    scOut[gn * 4 + tt] = v;
                }
            }
        }
    }
}

// ---------------------------------------------------------------------------
__global__ __launch_bounds__(256) void final_kernel(
    const u16* __restrict__ jkB, const float* __restrict__ scores,
    const float* __restrict__ Wout, float* __restrict__ out, int N)
{
    __shared__ float feS[4][64];
    int t = threadIdx.x, l = t & 63, w = t >> 6;
    long n = (long)blockIdx.x * 4 + w;
    bool ok = (n < N);
    long nn = ok ? n : (long)(N - 1);
    float sc[4];
#pragma unroll
    for (int tt = 0; tt < 4; ++tt)
        sc[tt] = scores[nn * 4 + tt] + scores[(long)N * 4 + nn * 4 + tt];
    float m = fmaxf(fmaxf(sc[0], sc[1]), fmaxf(sc[2], sc[3]));
    float e0 = __expf(sc[0] - m), e1 = __expf(sc[1] - m);
    float e2 = __expf(sc[2] - m), e3 = __expf(sc[3] - m);
    float den = e0 + e1 + e2 + e3;
    float a0 = e0 / den, a1 = e1 / den, a2 = e2 / den, a3 = e3 / den;
    float fe = a0 * bf2f(jkB[nn * 64 + l]) + a1 * bf2f(jkB[((long)N + nn) * 64 + l]) +
               a2 * bf2f(jkB[((long)2 * N + nn) * 64 + l]) +
               a3 * bf2f(jkB[((long)3 * N + nn) * 64 + l]);
    feS[w][l] = fe;
    __syncthreads();
    float logit = 0.f;
    if (l < 40)
        for (int c = 0; c < 64; ++c) logit += feS[w][c] * Wout[l * 64 + c];
    float v = (l < 40) ? logit : -1e30f;
    for (int off = 32; off; off >>= 1) v = fmaxf(v, __shfl_xor(v, off));
    float ex = (l < 40) ? __expf(logit - v) : 0.f;
    for (int off = 32; off; off >>= 1) ex += __shfl_xor(ex, off);
    if (ok && l < 40) out[n * 40 + l] = logit - v - __logf(ex);
}

// ---------------------------------------------------------------------------
extern "C" void kernel_launch(void* const* d_in, const int* in_sizes, int n_in,
                              void* d_out, int out_size, void* d_ws, size_t ws_size,
                              hipStream_t stream)
{
    const float* x        = (const float*)d_in[0];
    const int*   eig      = (const int*)d_in[1];
    const float* eag      = (const float*)d_in[2];
    const int*   eilg     = (const int*)d_in[3];
    const float* ealg     = (const float*)d_in[4];
    const float* W_feat   = (const float*)d_in[5];
    const float* W_msg    = (const float*)d_in[6];
    const float* W_lg2g   = (const float*)d_in[7];
    const float* b_lg2g   = (const float*)d_in[8];
    const float* W_msg_l  = (const float*)d_in[9];
    const float* Wih_f    = (const float*)d_in[10];
    const float* Whh_f    = (const float*)d_in[11];
    const float* bih_f    = (const float*)d_in[12];
    const float* bhh_f    = (const float*)d_in[13];
    const float* Wih_b    = (const float*)d_in[14];
    const float* Whh_b    = (const float*)d_in[15];
    const float* bih_b    = (const float*)d_in[16];
    const float* bhh_b    = (const float*)d_in[17];
    const float* W_att    = (const float*)d_in[18];
    const float* W_out    = (const float*)d_in[20];

    int  N   = in_sizes[0] / 128;
    long Eg  = in_sizes[1] / 2;
    long Elg = in_sizes[3] / 2;

    char* wp = (char*)d_ws;
    auto alloc = [&](size_t bytes) -> char* {
        char* p = wp; wp += (bytes + 255) & ~(size_t)255; return p;
    };
    u16*   jkB    = (u16*)  alloc((size_t)4 * N * 64 * 2);
    u16*   mA     = (u16*)  alloc((size_t)Eg * 64 * 2);
    u16*   mB     = (u16*)  alloc((size_t)Eg * 64 * 2);
    u16*   aggB   = (u16*)  alloc((size_t)N * 64 * 2);
    float* deg    = (float*)alloc((size_t)N * 4);
    float* scores = (float*)alloc((size_t)2 * N * 4 * 4);
    u16*   WhhB   = (u16*)  alloc((size_t)2 * 65536 * 2);
    u16*   WihB   = (u16*)  alloc((size_t)2 * 32768 * 2);
    float* BS     = (float*)alloc((size_t)2 * 512 * 4);
    u32*   off_g  = (u32*)  alloc((size_t)(N + 1) * 4);
    int*   list_g = (int*)  alloc((size_t)Eg * 4);
    u32*   off_lg = (u32*)  alloc((size_t)(Eg + 1) * 4);
    int*   list_lg= (int*)  alloc((size_t)Elg * 4);
    u32*   part   = (u32*)  alloc((size_t)1024 * 4);

    prep_w<<<772, 256, 0, stream>>>(Whh_f, Whh_b, Wih_f, Wih_b,
                                    bih_f, bhh_f, bih_b, bhh_b, WhhB, WihB, BS);
    // ---- CSR build: g-graph (dst over nodes) ----
    hipMemsetAsync(off_g, 0, (size_t)(N + 1) * 4, stream);
    count_kernel<<<(int)((Eg + 255) / 256), 256, 0, stream>>>(eig + Eg, off_g, Eg);
    {
        int nb = (N + 1023) / 1024;
        scan1<<<nb, 256, 0, stream>>>(off_g, part, N);
        scan2<<<1, 1024, 0, stream>>>(part, nb, off_g + N);
        scan3<<<nb, 256, 0, stream>>>(off_g, part, N);
    }
    fill_kernel<<<(int)((Eg + 255) / 256), 256, 0, stream>>>(eig + Eg, off_g, list_g, Eg);
    // ---- CSR build: lg-graph (dst over g-edges) ----
    hipMemsetAsync(off_lg, 0, (size_t)(Eg + 1) * 4, stream);
    count_kernel<<<(int)((Elg + 255) / 256), 256, 0, stream>>>(eilg + Elg, off_lg, Elg);
    {
        int nb = (int)((Eg + 1023) / 1024);
        scan1<<<nb, 256, 0, stream>>>(off_lg, part, (int)Eg);
        scan2<<<1, 1024, 0, stream>>>(part, nb, off_lg + Eg);
        scan3<<<nb, 256, 0, stream>>>(off_lg, part, (int)Eg);
    }
    fill_kernel<<<(int)((Elg + 255) / 256), 256, 0, stream>>>(eilg + Elg, off_lg, list_lg, Elg);

    // jk0 = relu(x @ W_feat^T)
    rowgemm<128, true, false><<<(N + 63) / 64, 256, 0, stream>>>(
        x, W_feat, nullptr, nullptr, jkB, N);
    // initial msgs -> mA (plain stores)
    edge_msg_init2<<<(int)((Eg + 127) / 128), 512, 0, stream>>>(
        jkB, eig, eag, W_msg, mA, Eg);
    // jk1 = gather(mA) @ W_lg2g^T + deg*b
    gather_g<<<(N + 7) / 8, 256, 0, stream>>>(mA, list_g, off_g, aggB, deg, N);
    rowgemm<64, false, true><<<(N + 63) / 64, 256, 0, stream>>>(
        aggB, W_lg2g, b_lg2g, deg, jkB + (size_t)N * 64, N);
    // ---- linegraph layer 0: mA -> mB ----
    zero_fill<<<(int)((Eg * 8 + 255) / 256), 256, 0, stream>>>(off_lg, mB, Eg);
    edge_msg_lg2<<<(int)((Elg + 127) / 128), 512, 0, stream>>>(
        mA, eilg, ealg, W_msg_l, list_lg, mB, Elg);
    gather_g<<<(N + 7) / 8, 256, 0, stream>>>(mB, list_g, off_g, aggB, nullptr, N);
    rowgemm<64, false, true><<<(N + 63) / 64, 256, 0, stream>>>(
        aggB, W_lg2g, b_lg2g, nullptr, jkB + (size_t)2 * N * 64, N);
    // ---- linegraph layer 1: mB -> mA ----
    zero_fill<<<(int)((Eg * 8 + 255) / 256), 256, 0, stream>>>(off_lg, mA, Eg);
    edge_msg_lg2<<<(int)((Elg + 127) / 128), 512, 0, stream>>>(
        mB, eilg, ealg, W_msg_l + 64 * 144, list_lg, mA, Elg);
    gather_g<<<(N + 7) / 8, 256, 0, stream>>>(mA, list_g, off_g, aggB, nullptr, N);
    rowgemm<64, false, true><<<(N + 63) / 64, 256, 0, stream>>>(
        aggB, W_lg2g, b_lg2g, nullptr, jkB + (size_t)3 * N * 64, N);
    // ---- JK bidirectional LSTM (register-resident weights, 64-node tiles) ----
    {
        int ntiles = (N + 63) / 64;
        lstm3<<<dim3(512, 2), 512, 0, stream>>>(
            jkB, WhhB, WihB, BS, W_att, scores, N, ntiles);
    }
    final_kernel<<<(N + 3) / 4, 256, 0, stream>>>(
        jkB, scores, W_out, (float*)d_out, N);
}